// Round 4
// baseline (1413.641 us; speedup 1.0000x reference)
//
#include <hip/hip_runtime.h>
#include <stdint.h>
#include <math.h>

#define B_ 16
#define T_ 2048
#define D_ 256
#define N_ (B_*T_*D_)   // 8388608

typedef __attribute__((ext_vector_type(8)))  __bf16 bf16x8;
typedef __attribute__((ext_vector_type(4)))  __bf16 bf16x4;
typedef __attribute__((ext_vector_type(2)))  __bf16 bf16x2;
typedef __attribute__((ext_vector_type(16))) float  float16;

// ---------------- JAX threefry2x32 (partitionable layout) ----------------
__device__ __forceinline__ uint32_t rotl32(uint32_t v, int r) {
  return (v << r) | (v >> (32 - r));
}

__device__ __forceinline__ void threefry2x32(uint32_t k0, uint32_t k1,
                                             uint32_t x0, uint32_t x1,
                                             uint32_t& o0, uint32_t& o1) {
  uint32_t ks2 = k0 ^ k1 ^ 0x1BD11BDAu;
#define TF_ROUND(r) { x0 += x1; x1 = rotl32(x1, r); x1 ^= x0; }
  x0 += k0; x1 += k1;
  TF_ROUND(13) TF_ROUND(15) TF_ROUND(26) TF_ROUND(6)
  x0 += k1; x1 += ks2 + 1u;
  TF_ROUND(17) TF_ROUND(29) TF_ROUND(16) TF_ROUND(24)
  x0 += ks2; x1 += k0 + 2u;
  TF_ROUND(13) TF_ROUND(15) TF_ROUND(26) TF_ROUND(6)
  x0 += k0; x1 += k1 + 3u;
  TF_ROUND(17) TF_ROUND(29) TF_ROUND(16) TF_ROUND(24)
  x0 += k1; x1 += ks2 + 4u;
  TF_ROUND(13) TF_ROUND(15) TF_ROUND(26) TF_ROUND(6)
  x0 += ks2; x1 += k0 + 5u;
#undef TF_ROUND
  o0 = x0; o1 = x1;
}

// XLA ErfInv f32 polynomial (Giles)
__device__ __forceinline__ float erfinv_xla(float x) {
  float w = -log1pf(-x * x);
  float p;
  if (w < 5.0f) {
    w -= 2.5f;
    p = 2.81022636e-08f;
    p = fmaf(p, w, 3.43273939e-07f);
    p = fmaf(p, w, -3.5233877e-06f);
    p = fmaf(p, w, -4.39150654e-06f);
    p = fmaf(p, w, 0.00021858087f);
    p = fmaf(p, w, -0.00125372503f);
    p = fmaf(p, w, -0.00417768164f);
    p = fmaf(p, w, 0.246640727f);
    p = fmaf(p, w, 1.50140941f);
  } else {
    w = sqrtf(w) - 3.0f;
    p = -0.000200214257f;
    p = fmaf(p, w, 0.000100950558f);
    p = fmaf(p, w, 0.00134934322f);
    p = fmaf(p, w, -0.00367342844f);
    p = fmaf(p, w, 0.00573950773f);
    p = fmaf(p, w, -0.0076224613f);
    p = fmaf(p, w, 0.00943887047f);
    p = fmaf(p, w, 1.00167406f);
    p = fmaf(p, w, 2.83297682f);
  }
  return p * x;
}

// jax.random.normal element n (flat row-major index), key=(0, seed)
__device__ __forceinline__ float jax_normal_elem(uint32_t key, uint32_t n) {
  uint32_t o0, o1;
  threefry2x32(0u, key, 0u, n, o0, o1);
  uint32_t bits = o0 ^ o1;                     // partitionable 32-bit output
  float f = __uint_as_float((bits >> 9) | 0x3f800000u) - 1.0f;  // [0,1)
  const float lo = -0.99999994f;               // nextafter(-1,0)
  float u = fmaxf(lo, fmaf(f, 2.0f, lo));      // (maxval-minval) rounds to 2.0f
  return 1.41421356f * erfinv_xla(u);          // sqrt(2) in f32
}

// ---------------- mean over T ----------------
__global__ __launch_bounds__(1024) void mean_k(const float* __restrict__ A,
    const float* __restrict__ Vv, float* __restrict__ muA, float* __restrict__ muV) {
  const float* X = blockIdx.y ? Vv : A;
  float* mu = blockIdx.y ? muV : muA;
  int b = blockIdx.x;
  int d = threadIdx.x & 255;
  int part = threadIdx.x >> 8;   // 0..3
  __shared__ float partial[4][256];
  const float* p = X + ((size_t)b*T_ + (size_t)part*(T_/4))*D_ + d;
  float s = 0.f;
  for (int t = 0; t < T_/4; ++t) s += p[(size_t)t * D_];
  partial[part][d] = s;
  __syncthreads();
  if (part == 0)
    mu[b*D_ + d] = (partial[0][d] + partial[1][d] + partial[2][d] + partial[3][d]) * (1.0f/(float)T_);
}

// ---------------- Sigma = Xc^T Xc / (T-1), lower tiles only, +jitter on diag ----------------
__global__ __launch_bounds__(256) void sigma_k(const float* __restrict__ A,
    const float* __restrict__ Vv, const float* __restrict__ muA,
    const float* __restrict__ muV, float* __restrict__ SA, float* __restrict__ SV) {
  const float* X  = blockIdx.z ? Vv  : A;
  const float* mu = blockIdx.z ? muV : muA;
  float* Sg       = blockIdx.z ? SV  : SA;
  const int TIa[10] = {0,1,1,2,2,2,3,3,3,3};
  const int TJa[10] = {0,0,1,0,1,2,0,1,2,3};
  int b = blockIdx.y;
  int I0 = TIa[blockIdx.x]*64, J0 = TJa[blockIdx.x]*64;
  __shared__ float xi[16][64];
  __shared__ float xj[16][64];
  int tid = threadIdx.x;
  int r = tid >> 4, c4 = (tid & 15) * 4;
  float4 mI = *(const float4*)(mu + b*D_ + I0 + c4);
  float4 mJ = *(const float4*)(mu + b*D_ + J0 + c4);
  float acc[4][4] = {};
  int i4 = (tid >> 4) * 4, j4 = (tid & 15) * 4;
  for (int t0 = 0; t0 < T_; t0 += 16) {
    __syncthreads();
    const float* px = X + ((size_t)b*T_ + t0 + r) * D_;
    float4 fa = *(const float4*)(px + I0 + c4);
    xi[r][c4+0] = fa.x - mI.x; xi[r][c4+1] = fa.y - mI.y;
    xi[r][c4+2] = fa.z - mI.z; xi[r][c4+3] = fa.w - mI.w;
    float4 fb = *(const float4*)(px + J0 + c4);
    xj[r][c4+0] = fb.x - mJ.x; xj[r][c4+1] = fb.y - mJ.y;
    xj[r][c4+2] = fb.z - mJ.z; xj[r][c4+3] = fb.w - mJ.w;
    __syncthreads();
    #pragma unroll
    for (int t = 0; t < 16; ++t) {
      float4 qa = *(const float4*)&xi[t][i4];
      float4 qb = *(const float4*)&xj[t][j4];
      acc[0][0] = fmaf(qa.x, qb.x, acc[0][0]); acc[0][1] = fmaf(qa.x, qb.y, acc[0][1]);
      acc[0][2] = fmaf(qa.x, qb.z, acc[0][2]); acc[0][3] = fmaf(qa.x, qb.w, acc[0][3]);
      acc[1][0] = fmaf(qa.y, qb.x, acc[1][0]); acc[1][1] = fmaf(qa.y, qb.y, acc[1][1]);
      acc[1][2] = fmaf(qa.y, qb.z, acc[1][2]); acc[1][3] = fmaf(qa.y, qb.w, acc[1][3]);
      acc[2][0] = fmaf(qa.z, qb.x, acc[2][0]); acc[2][1] = fmaf(qa.z, qb.y, acc[2][1]);
      acc[2][2] = fmaf(qa.z, qb.z, acc[2][2]); acc[2][3] = fmaf(qa.z, qb.w, acc[2][3]);
      acc[3][0] = fmaf(qa.w, qb.x, acc[3][0]); acc[3][1] = fmaf(qa.w, qb.y, acc[3][1]);
      acc[3][2] = fmaf(qa.w, qb.z, acc[3][2]); acc[3][3] = fmaf(qa.w, qb.w, acc[3][3]);
    }
  }
  const float inv = 1.0f / (float)(T_ - 1);
  float* out = Sg + (size_t)b*D_*D_;
  #pragma unroll
  for (int ii = 0; ii < 4; ++ii)
    #pragma unroll
    for (int jj = 0; jj < 4; ++jj) {
      int row = I0 + i4 + ii, col = J0 + j4 + jj;
      float v = acc[ii][jj] * inv;
      if (row == col) v += 1e-6f;
      out[(size_t)row*D_ + col] = v;
    }
}

// ---------------- blocked Cholesky: 2-row GEMM blocking + wave-sync diag factor + parallel TRSM ----
// One block per (batch, modality). Thread t<128 owns rows 2t, 2t+1.
// Per panel J (NB=32): (1) GEMM update acc -= L[rows,<J] * L[J:J+32,<J]^T with B staged in LDS
// (32-wide chunks, each LDS read feeds 2 rows); (2) threads 0-31 factor the 32x32 diag block
// right-looking entirely in registers via shfl broadcasts (no barriers) and write those rows to
// global; (3) remaining rows forward-substitute against the strictly-lower block in LDS.
#define CNB 32

__global__ __launch_bounds__(256) void chol_k(float* __restrict__ SA, float* __restrict__ SV) {
  float* M = (blockIdx.y ? SV : SA) + (size_t)blockIdx.x * D_ * D_;
  __shared__ float SB[CNB][36];      // staged B-panel chunk (diag-block rows, k-chunk)
  __shared__ float PDiag[CNB][36];   // GEMM-updated diag block routed to factor lanes
  __shared__ float PL[CNB][36];      // factored diag block, STRICTLY lower (diag+upper = 0)
  __shared__ float PDinv[CNB];       // 1/diag

  const int tid = threadIdx.x;
  const int r0i = 2 * tid;           // first owned row (tid < 128)
  float* row0 = M + (size_t)r0i * D_;
  float* row1 = row0 + D_;

  for (int J = 0; J < D_; J += CNB) {
    const bool own = (tid < 128) && (r0i >= J);
    const bool diagown = own && (r0i < J + CNB);
    float acc0[CNB], acc1[CNB];
    if (own) {
      #pragma unroll
      for (int q = 0; q < CNB; q += 4) {
        float4 f0 = *(const float4*)(row0 + J + q);
        acc0[q]=f0.x; acc0[q+1]=f0.y; acc0[q+2]=f0.z; acc0[q+3]=f0.w;
        float4 f1 = *(const float4*)(row1 + J + q);
        acc1[q]=f1.x; acc1[q+1]=f1.y; acc1[q+2]=f1.z; acc1[q+3]=f1.w;
      }
    }
    // ---- GEMM update over finalized columns k < J ----
    for (int k0 = 0; k0 < J; k0 += 32) {
      __syncthreads();
      {  // stage SB[jj][c] = L[J+jj, k0+c] : 1024 elems, one float4/thread
        int jj = tid >> 3, c = (tid & 7) * 4;
        float4 f = *(const float4*)(M + (size_t)(J + jj) * D_ + k0 + c);
        *(float4*)&SB[jj][c] = f;
      }
      __syncthreads();
      if (own) {
        float lv0[32], lv1[32];
        #pragma unroll
        for (int q = 0; q < 32; q += 4) {
          float4 f0 = *(const float4*)(row0 + k0 + q);
          lv0[q]=f0.x; lv0[q+1]=f0.y; lv0[q+2]=f0.z; lv0[q+3]=f0.w;
          float4 f1 = *(const float4*)(row1 + k0 + q);
          lv1[q]=f1.x; lv1[q+1]=f1.y; lv1[q+2]=f1.z; lv1[q+3]=f1.w;
        }
        #pragma unroll
        for (int jj = 0; jj < CNB; ++jj) {
          float s0 = 0.f, s1 = 0.f;
          #pragma unroll
          for (int c = 0; c < 32; c += 4) {
            float4 b = *(const float4*)&SB[jj][c];
            s0 = fmaf(lv0[c],   b.x, s0); s0 = fmaf(lv0[c+1], b.y, s0);
            s0 = fmaf(lv0[c+2], b.z, s0); s0 = fmaf(lv0[c+3], b.w, s0);
            s1 = fmaf(lv1[c],   b.x, s1); s1 = fmaf(lv1[c+1], b.y, s1);
            s1 = fmaf(lv1[c+2], b.z, s1); s1 = fmaf(lv1[c+3], b.w, s1);
          }
          acc0[jj] -= s0; acc1[jj] -= s1;
        }
      }
    }
    __syncthreads();
    // ---- route diag-block rows to LDS ----
    if (diagown) {
      int dr = r0i - J;
      #pragma unroll
      for (int q = 0; q < CNB; q += 4) {
        *(float4*)&PDiag[dr][q]   = make_float4(acc0[q], acc0[q+1], acc0[q+2], acc0[q+3]);
        *(float4*)&PDiag[dr+1][q] = make_float4(acc1[q], acc1[q+1], acc1[q+2], acc1[q+3]);
      }
    }
    __syncthreads();
    // ---- wave-synchronous right-looking factor of the 32x32 diag block (threads 0-31) ----
    if (tid < 32) {
      const int r = tid;
      float a[CNB];
      #pragma unroll
      for (int q = 0; q < CNB; q += 4) {
        float4 f = *(const float4*)&PDiag[r][q];
        a[q]=f.x; a[q+1]=f.y; a[q+2]=f.z; a[q+3]=f.w;
      }
      #pragma unroll
      for (int j = 0; j < CNB; ++j) {
        float ajj = __shfl(a[j], j);         // uniform broadcast of fully-updated diag elem
        float d = sqrtf(ajj);
        float dinv = 1.0f / d;
        float lcol = (r == j) ? d : a[j] * dinv;   // column j finalized (valid for r >= j)
        a[j] = lcol;
        if (r == j) PDinv[j] = dinv;
        #pragma unroll
        for (int k = j + 1; k < CNB; ++k) {
          float lkj = __shfl(lcol, k);       // L[k][j]
          a[k] = fmaf(-lcol, lkj, a[k]);     // trailing update
        }
      }
      // write strictly-lower block to LDS (diag+upper zero) for TRSM
      #pragma unroll
      for (int q = 0; q < CNB; q += 4) {
        float4 o;
        o.x = (q   < r) ? a[q]   : 0.f;
        o.y = (q+1 < r) ? a[q+1] : 0.f;
        o.z = (q+2 < r) ? a[q+2] : 0.f;
        o.w = (q+3 < r) ? a[q+3] : 0.f;
        *(float4*)&PL[r][q] = o;
      }
      // write diag row J+r to global: lower incl diag from a[], upper zeros
      float* grow = M + (size_t)(J + r) * D_ + J;
      #pragma unroll
      for (int q = 0; q < CNB; q += 4) {
        float4 o;
        o.x = (q   <= r) ? a[q]   : 0.f;
        o.y = (q+1 <= r) ? a[q+1] : 0.f;
        o.z = (q+2 <= r) ? a[q+2] : 0.f;
        o.w = (q+3 <= r) ? a[q+3] : 0.f;
        *(float4*)(grow + q) = o;
      }
    }
    __syncthreads();
    // ---- parallel TRSM for rows below the diag block (in-register forward substitution) ----
    if (own && !diagown) {
      #pragma unroll
      for (int j = 0; j < CNB; ++j) {
        float s0 = 0.f, s1 = 0.f;
        const int cq = (j + 3) >> 2;         // quads covering k < j (zero-padded partials)
        #pragma unroll
        for (int c = 0; c < 8; ++c) {
          if (c < cq) {
            float4 b = *(const float4*)&PL[j][c*4];
            s0 = fmaf(acc0[c*4],   b.x, s0); s0 = fmaf(acc0[c*4+1], b.y, s0);
            s0 = fmaf(acc0[c*4+2], b.z, s0); s0 = fmaf(acc0[c*4+3], b.w, s0);
            s1 = fmaf(acc1[c*4],   b.x, s1); s1 = fmaf(acc1[c*4+1], b.y, s1);
            s1 = fmaf(acc1[c*4+2], b.z, s1); s1 = fmaf(acc1[c*4+3], b.w, s1);
          }
        }
        float di = PDinv[j];
        acc0[j] = (acc0[j] - s0) * di;
        acc1[j] = (acc1[j] - s1) * di;
      }
      #pragma unroll
      for (int q = 0; q < CNB; q += 4) {
        *(float4*)(row0 + J + q) = make_float4(acc0[q], acc0[q+1], acc0[q+2], acc0[q+3]);
        *(float4*)(row1 + J + q) = make_float4(acc1[q], acc1[q+1], acc1[q+2], acc1[q+3]);
      }
    }
    __syncthreads();   // panel finalized in global before it serves as B next iteration
  }
  // zero remaining upper triangle (cols beyond each row's panel band)
  for (int k = tid + 1; k < D_; ++k) M[(size_t)tid * D_ + k] = 0.f;
}

// ---------------- K = mu + eps @ L^T with on-the-fly eps generation ----------------
__global__ __launch_bounds__(256) void kgen_k(const float* __restrict__ L,
    const float* __restrict__ mu, float* __restrict__ Kout, uint32_t key) {
  __shared__ float eps[64][16];
  int b = blockIdx.y;
  int t0 = blockIdx.x * 64;
  int e = threadIdx.x;
  const float* Lr = L + (size_t)b*D_*D_ + (size_t)e*D_;
  float acc[64];
  #pragma unroll
  for (int t = 0; t < 64; ++t) acc[t] = 0.f;
  int gt = threadIdx.x >> 2;
  int gd = (threadIdx.x & 3) * 4;
  for (int d0 = 0; d0 < D_; d0 += 16) {
    __syncthreads();
    uint32_t nbase = ((uint32_t)(b*T_ + t0 + gt)) * (uint32_t)D_ + (uint32_t)(d0 + gd);
    #pragma unroll
    for (int q = 0; q < 4; ++q) eps[gt][gd+q] = jax_normal_elem(key, nbase + q);
    __syncthreads();
    float lreg[16];
    #pragma unroll
    for (int q = 0; q < 16; q += 4) {
      float4 f = *(const float4*)(Lr + d0 + q);
      lreg[q] = f.x; lreg[q+1] = f.y; lreg[q+2] = f.z; lreg[q+3] = f.w;
    }
    #pragma unroll 8
    for (int t = 0; t < 64; ++t) {
      float s = acc[t];
      #pragma unroll
      for (int dd = 0; dd < 16; ++dd) s = fmaf(eps[t][dd], lreg[dd], s);
      acc[t] = s;
    }
  }
  float m = mu[b*D_ + e];
  for (int t = 0; t < 64; ++t)
    Kout[((size_t)b*T_ + t0 + t)*D_ + e] = acc[t] + m;
}

// ---------------- MFMA flash attention: O = softmax(Q K^T / 16) V ----------------
// 64 Q-rows per block, 4 waves; wave w: S-block rows (w>>1)*32, cols (w&1)*32;
//                                 O-strip rows (w>>1)*32, cols (w&1)*128.
#define SCALE_ 0.0625f
#define KSTR 264    // bf16 elems/row: 528 B = rot-4 banking -> conflict-free b128 col reads
#define SFSTR 68    // f32 elems/row
#define PSTR 72     // bf16 elems/row: 144 B = rot-4 banking

__global__ __launch_bounds__(256, 2) void attn_mfma(const float* __restrict__ Qg,
    const float* __restrict__ Kg, const float* __restrict__ Vg,
    float* __restrict__ Og) {
  __shared__ __bf16 KS[64 * KSTR];       // 33792 B
  __shared__ float  Sf[64 * SFSTR];      // 17408 B
  __shared__ __bf16 Ps[64 * PSTR];       //  9216 B
  __shared__ float rowm[64], rowl[64], rowa[64];  // 768 B

  const int tid  = threadIdx.x;
  const int wv   = tid >> 6;
  const int lane = tid & 63;
  const int ln31 = lane & 31;
  const int h8   = (lane >> 5) * 8;     // k-group offset within frag
  const int qb   = (wv >> 1) * 32;      // this wave's Q-row base
  const int sb   = (wv & 1) * 32;       // this wave's S-col (key) base
  const int cb   = (wv & 1) * 128;      // this wave's O-col base
  const int b    = blockIdx.y;
  const int t0   = blockIdx.x * 64;

  // ---- Q into registers as bf16 A-frags (row = qb+ln31, k = dstep*16+h8+j) ----
  bf16x8 qf[16];
  {
    const float* qrow = Qg + ((size_t)b*T_ + t0 + qb + ln31) * D_;
    #pragma unroll
    for (int s = 0; s < 16; ++s) {
      float4 f0 = *(const float4*)(qrow + s*16 + h8);
      float4 f1 = *(const float4*)(qrow + s*16 + h8 + 4);
      bf16x8 q;
      q[0] = (__bf16)f0.x; q[1] = (__bf16)f0.y; q[2] = (__bf16)f0.z; q[3] = (__bf16)f0.w;
      q[4] = (__bf16)f1.x; q[5] = (__bf16)f1.y; q[6] = (__bf16)f1.z; q[7] = (__bf16)f1.w;
      qf[s] = q;
    }
  }
  if (tid < 64) { rowm[tid] = -INFINITY; rowl[tid] = 0.f; }

  float16 oacc[4];
  #pragma unroll
  for (int nb = 0; nb < 4; ++nb)
    #pragma unroll
    for (int i = 0; i < 16; ++i) oacc[nb][i] = 0.f;

  for (int s0 = 0; s0 < T_; s0 += 64) {
    __syncthreads();
    // ---- stage K tile (f32 global, coalesced -> bf16 LDS) ----
    #pragma unroll
    for (int it = 0; it < 16; ++it) {
      int flat = it*1024 + tid*4;
      int r = flat >> 8, c = flat & 255;
      float4 f = *(const float4*)(Kg + ((size_t)b*T_ + s0 + r)*D_ + c);
      bf16x4 u;
      u[0] = (__bf16)f.x; u[1] = (__bf16)f.y; u[2] = (__bf16)f.z; u[3] = (__bf16)f.w;
      *(bf16x4*)&KS[r*KSTR + c] = u;
    }
    __syncthreads();
    // ---- S = Q K^T (one 32x32 block per wave) ----
    float16 sacc = {0.f,0.f,0.f,0.f,0.f,0.f,0.f,0.f,0.f,0.f,0.f,0.f,0.f,0.f,0.f,0.f};
    #pragma unroll
    for (int d = 0; d < 16; ++d) {
      bf16x8 kf = *(const bf16x8*)&KS[(sb + ln31)*KSTR + d*16 + h8];
      sacc = __builtin_amdgcn_mfma_f32_32x32x16_bf16(qf[d], kf, sacc, 0, 0, 0);
    }
    #pragma unroll
    for (int r = 0; r < 16; ++r) {
      int row = qb + (r & 3) + 8*(r >> 2) + 4*(lane >> 5);
      Sf[row*SFSTR + sb + ln31] = sacc[r] * SCALE_;
    }
    __syncthreads();
    // ---- online softmax: 4 threads per row, 16 cols each ----
    {
      int r = tid >> 2, sub = tid & 3;
      const float* srow = &Sf[r*SFSTR + sub*16];
      float4 a0 = *(const float4*)(srow);
      float4 a1 = *(const float4*)(srow + 4);
      float4 a2 = *(const float4*)(srow + 8);
      float4 a3 = *(const float4*)(srow + 12);
      float xv[16] = {a0.x,a0.y,a0.z,a0.w, a1.x,a1.y,a1.z,a1.w,
                      a2.x,a2.y,a2.z,a2.w, a3.x,a3.y,a3.z,a3.w};
      float mloc = xv[0];
      #pragma unroll
      for (int i = 1; i < 16; ++i) mloc = fmaxf(mloc, xv[i]);
      mloc = fmaxf(mloc, __shfl_xor(mloc, 1));
      mloc = fmaxf(mloc, __shfl_xor(mloc, 2));
      float mold = rowm[r];
      float mnew = fmaxf(mold, mloc);
      float ls = 0.f;
      #pragma unroll
      for (int i = 0; i < 16; ++i) { xv[i] = expf(xv[i] - mnew); ls += xv[i]; }
      #pragma unroll
      for (int i = 0; i < 8; ++i) {
        bf16x2 t2; t2[0] = (__bf16)xv[2*i]; t2[1] = (__bf16)xv[2*i+1];
        *(bf16x2*)&Ps[r*PSTR + sub*16 + 2*i] = t2;
      }
      ls += __shfl_xor(ls, 1);
      ls += __shfl_xor(ls, 2);
      if (sub == 0) {
        float al = expf(mold - mnew);
        rowa[r] = al;
        rowl[r] = rowl[r] * al + ls;
        rowm[r] = mnew;
      }
    }
    __syncthreads();
    // ---- rescale O by alpha ----
    #pragma unroll
    for (int r = 0; r < 16; ++r) {
      float al = rowa[qb + (r & 3) + 8*(r >> 2) + 4*(lane >> 5)];
      oacc[0][r] *= al; oacc[1][r] *= al; oacc[2][r] *= al; oacc[3][r] *= al;
    }
    // ---- O += P V  (P from LDS, V frags straight from global/L2) ----
    #pragma unroll
    for (int ks = 0; ks < 4; ++ks) {
      bf16x8 pf = *(const bf16x8*)&Ps[(qb + ln31)*PSTR + ks*16 + h8];
      const float* vbase = Vg + ((size_t)b*T_ + s0 + ks*16 + h8)*D_ + cb + ln31;
      #pragma unroll
      for (int nb = 0; nb < 4; ++nb) {
        const float* vcol = vbase + nb*32;
        bf16x8 vf;
        #pragma unroll
        for (int j = 0; j < 8; ++j) vf[j] = (__bf16)vcol[(size_t)j * D_];
        oacc[nb] = __builtin_amdgcn_mfma_f32_32x32x16_bf16(pf, vf, oacc[nb], 0, 0, 0);
      }
    }
  }
  // ---- epilogue: O /= l, store ----
  #pragma unroll
  for (int r = 0; r < 16; ++r) {
    int row = qb + (r & 3) + 8*(r >> 2) + 4*(lane >> 5);
    float inv = 1.0f / rowl[row];
    float* orow = Og + ((size_t)b*T_ + t0 + row)*D_ + cb + ln31;
    orow[0]  = oacc[0][r] * inv;
    orow[32] = oacc[1][r] * inv;
    orow[64] = oacc[2][r] * inv;
    orow[96] = oacc[3][r] * inv;
  }
}

// ---------------- gates + cosine combine (one wave per (b,t) row) ----------------
__global__ __launch_bounds__(256) void comb_k(const float* __restrict__ A,
    const float* __restrict__ Vv, const float* __restrict__ att1,
    const float* __restrict__ att2, const float* __restrict__ WA,
    const float* __restrict__ WV, const float* __restrict__ bA,
    const float* __restrict__ bV, float* __restrict__ out) {
  int wv = threadIdx.x >> 6;
  int lane = threadIdx.x & 63;
  size_t row = (size_t)blockIdx.x * 4 + wv;
  size_t base = row * D_;
  int d = lane * 4;
  float4 a  = *(const float4*)(A + base + d);
  float4 v  = *(const float4*)(Vv + base + d);
  float4 x  = *(const float4*)(att1 + base + d);
  float4 y  = *(const float4*)(att2 + base + d);
  float4 w1 = *(const float4*)(WA + d);
  float4 w2 = *(const float4*)(WA + 256 + d);
  float4 w3 = *(const float4*)(WV + d);
  float4 w4 = *(const float4*)(WV + 256 + d);
  float sga = a.x*w1.x + a.y*w1.y + a.z*w1.z + a.w*w1.w
            + x.x*w2.x + x.y*w2.y + x.z*w2.z + x.w*w2.w;
  float sgv = v.x*w3.x + v.y*w3.y + v.z*w3.z + v.w*w3.w
            + y.x*w4.x + y.y*w4.y + y.z*w4.z + y.w*w4.w;
  float sav = a.x*v.x + a.y*v.y + a.z*v.z + a.w*v.w;
  float saa = a.x*a.x + a.y*a.y + a.z*a.z + a.w*a.w;
  float svv = v.x*v.x + v.y*v.y + v.z*v.z + v.w*v.w;
  #pragma unroll
  for (int m = 32; m; m >>= 1) {
    sga += __shfl_xor(sga, m);
    sgv += __shfl_xor(sgv, m);
    sav += __shfl_xor(sav, m);
    saa += __shfl_xor(saa, m);
    svv += __shfl_xor(svv, m);
  }
  float gA = 1.0f / (1.0f + expf(-(sga + bA[0])));
  float gV = 1.0f / (1.0f + expf(-(sgv + bV[0])));
  float cs = sav / fmaxf(sqrtf(saa) * sqrtf(svv), 1e-8f);
  float al = 1.0f / (1.0f + expf(-cs));
  float be = 1.0f - al;
  float4 o;
  o.x = al * (gA*a.x + (1.0f-gA)*x.x) + be * (gV*v.x + (1.0f-gV)*y.x);
  o.y = al * (gA*a.y + (1.0f-gA)*x.y) + be * (gV*v.y + (1.0f-gV)*y.y);
  o.z = al * (gA*a.z + (1.0f-gA)*x.z) + be * (gV*v.z + (1.0f-gV)*y.z);
  o.w = al * (gA*a.w + (1.0f-gA)*x.w) + be * (gV*v.w + (1.0f-gV)*y.w);
  *(float4*)(out + base + d) = o;
}

extern "C" void kernel_launch(void* const* d_in, const int* in_sizes, int n_in,
                              void* d_out, int out_size, void* d_ws, size_t ws_size,
                              hipStream_t stream) {
  (void)in_sizes; (void)n_in; (void)out_size; (void)ws_size;
  const float* A  = (const float*)d_in[0];
  const float* V  = (const float*)d_in[1];
  const float* WA = (const float*)d_in[2];
  const float* WV = (const float*)d_in[3];
  const float* bA = (const float*)d_in[4];
  const float* bV = (const float*)d_in[5];
  float* ws  = (float*)d_ws;
  float* muA = ws;                                  // 4096
  float* muV = muA + 4096;                          // 4096
  float* LA  = muV + 4096;                          // 16*256*256
  float* LV  = LA + (size_t)B_*D_*D_;               // 16*256*256
  float* Kb  = LV + (size_t)B_*D_*D_;               // N_ (K_v then reused for K_a)
  float* at1 = Kb + (size_t)N_;                     // N_ att_av
  float* at2 = at1 + (size_t)N_;                    // N_ att_va
  // total ws: 27,271,168 floats = ~104 MB

  mean_k<<<dim3(16,2), dim3(1024), 0, stream>>>(A, V, muA, muV);
  sigma_k<<<dim3(10,16,2), dim3(256), 0, stream>>>(A, V, muA, muV, LA, LV);
  chol_k<<<dim3(16,2), dim3(256), 0, stream>>>(LA, LV);
  // K_v = resample(V, key 42): audio queries attend to it, values = V
  kgen_k<<<dim3(32,16), dim3(256), 0, stream>>>(LV, muV, Kb, 42u);
  attn_mfma<<<dim3(32,16), dim3(256), 0, stream>>>(A, Kb, V, at1);
  // K_a = resample(A, key 43): visual queries attend to it, values = A
  kgen_k<<<dim3(32,16), dim3(256), 0, stream>>>(LA, muA, Kb, 43u);
  attn_mfma<<<dim3(32,16), dim3(256), 0, stream>>>(V, Kb, A, at2);
  comb_k<<<dim3(8192), dim3(256), 0, stream>>>(A, V, at1, at2, WA, WV, bA, bV, (float*)d_out);
}

// Round 6
// 1308.340 us; speedup vs baseline: 1.0805x; 1.0805x over previous
//
#include <hip/hip_runtime.h>
#include <stdint.h>
#include <math.h>

#define B_ 16
#define T_ 2048
#define D_ 256
#define N_ (B_*T_*D_)   // 8388608

typedef __attribute__((ext_vector_type(8)))  __bf16 bf16x8;
typedef __attribute__((ext_vector_type(4)))  __bf16 bf16x4;
typedef __attribute__((ext_vector_type(2)))  __bf16 bf16x2;
typedef __attribute__((ext_vector_type(16))) float  float16;

// ---------------- JAX threefry2x32 (partitionable layout) ----------------
__device__ __forceinline__ uint32_t rotl32(uint32_t v, int r) {
  return (v << r) | (v >> (32 - r));
}

__device__ __forceinline__ void threefry2x32(uint32_t k0, uint32_t k1,
                                             uint32_t x0, uint32_t x1,
                                             uint32_t& o0, uint32_t& o1) {
  uint32_t ks2 = k0 ^ k1 ^ 0x1BD11BDAu;
#define TF_ROUND(r) { x0 += x1; x1 = rotl32(x1, r); x1 ^= x0; }
  x0 += k0; x1 += k1;
  TF_ROUND(13) TF_ROUND(15) TF_ROUND(26) TF_ROUND(6)
  x0 += k1; x1 += ks2 + 1u;
  TF_ROUND(17) TF_ROUND(29) TF_ROUND(16) TF_ROUND(24)
  x0 += ks2; x1 += k0 + 2u;
  TF_ROUND(13) TF_ROUND(15) TF_ROUND(26) TF_ROUND(6)
  x0 += k0; x1 += k1 + 3u;
  TF_ROUND(17) TF_ROUND(29) TF_ROUND(16) TF_ROUND(24)
  x0 += k1; x1 += ks2 + 4u;
  TF_ROUND(13) TF_ROUND(15) TF_ROUND(26) TF_ROUND(6)
  x0 += ks2; x1 += k0 + 5u;
#undef TF_ROUND
  o0 = x0; o1 = x1;
}

// XLA ErfInv f32 polynomial (Giles)
__device__ __forceinline__ float erfinv_xla(float x) {
  float w = -log1pf(-x * x);
  float p;
  if (w < 5.0f) {
    w -= 2.5f;
    p = 2.81022636e-08f;
    p = fmaf(p, w, 3.43273939e-07f);
    p = fmaf(p, w, -3.5233877e-06f);
    p = fmaf(p, w, -4.39150654e-06f);
    p = fmaf(p, w, 0.00021858087f);
    p = fmaf(p, w, -0.00125372503f);
    p = fmaf(p, w, -0.00417768164f);
    p = fmaf(p, w, 0.246640727f);
    p = fmaf(p, w, 1.50140941f);
  } else {
    w = sqrtf(w) - 3.0f;
    p = -0.000200214257f;
    p = fmaf(p, w, 0.000100950558f);
    p = fmaf(p, w, 0.00134934322f);
    p = fmaf(p, w, -0.00367342844f);
    p = fmaf(p, w, 0.00573950773f);
    p = fmaf(p, w, -0.0076224613f);
    p = fmaf(p, w, 0.00943887047f);
    p = fmaf(p, w, 1.00167406f);
    p = fmaf(p, w, 2.83297682f);
  }
  return p * x;
}

// jax.random.normal element n (flat row-major index), key=(0, seed)
__device__ __forceinline__ float jax_normal_elem(uint32_t key, uint32_t n) {
  uint32_t o0, o1;
  threefry2x32(0u, key, 0u, n, o0, o1);
  uint32_t bits = o0 ^ o1;                     // partitionable 32-bit output
  float f = __uint_as_float((bits >> 9) | 0x3f800000u) - 1.0f;  // [0,1)
  const float lo = -0.99999994f;               // nextafter(-1,0)
  float u = fmaxf(lo, fmaf(f, 2.0f, lo));      // (maxval-minval) rounds to 2.0f
  return 1.41421356f * erfinv_xla(u);          // sqrt(2) in f32
}

// ---------------- mean over T ----------------
__global__ __launch_bounds__(1024) void mean_k(const float* __restrict__ A,
    const float* __restrict__ Vv, float* __restrict__ muA, float* __restrict__ muV) {
  const float* X = blockIdx.y ? Vv : A;
  float* mu = blockIdx.y ? muV : muA;
  int b = blockIdx.x;
  int d = threadIdx.x & 255;
  int part = threadIdx.x >> 8;   // 0..3
  __shared__ float partial[4][256];
  const float* p = X + ((size_t)b*T_ + (size_t)part*(T_/4))*D_ + d;
  float s = 0.f;
  for (int t = 0; t < T_/4; ++t) s += p[(size_t)t * D_];
  partial[part][d] = s;
  __syncthreads();
  if (part == 0)
    mu[b*D_ + d] = (partial[0][d] + partial[1][d] + partial[2][d] + partial[3][d]) * (1.0f/(float)T_);
}

// ---------------- Sigma = Xc^T Xc / (T-1), lower tiles only, +jitter on diag ----------------
__global__ __launch_bounds__(256) void sigma_k(const float* __restrict__ A,
    const float* __restrict__ Vv, const float* __restrict__ muA,
    const float* __restrict__ muV, float* __restrict__ SA, float* __restrict__ SV) {
  const float* X  = blockIdx.z ? Vv  : A;
  const float* mu = blockIdx.z ? muV : muA;
  float* Sg       = blockIdx.z ? SV  : SA;
  const int TIa[10] = {0,1,1,2,2,2,3,3,3,3};
  const int TJa[10] = {0,0,1,0,1,2,0,1,2,3};
  int b = blockIdx.y;
  int I0 = TIa[blockIdx.x]*64, J0 = TJa[blockIdx.x]*64;
  __shared__ float xi[16][64];
  __shared__ float xj[16][64];
  int tid = threadIdx.x;
  int r = tid >> 4, c4 = (tid & 15) * 4;
  float4 mI = *(const float4*)(mu + b*D_ + I0 + c4);
  float4 mJ = *(const float4*)(mu + b*D_ + J0 + c4);
  float acc[4][4] = {};
  int i4 = (tid >> 4) * 4, j4 = (tid & 15) * 4;
  for (int t0 = 0; t0 < T_; t0 += 16) {
    __syncthreads();
    const float* px = X + ((size_t)b*T_ + t0 + r) * D_;
    float4 fa = *(const float4*)(px + I0 + c4);
    xi[r][c4+0] = fa.x - mI.x; xi[r][c4+1] = fa.y - mI.y;
    xi[r][c4+2] = fa.z - mI.z; xi[r][c4+3] = fa.w - mI.w;
    float4 fb = *(const float4*)(px + J0 + c4);
    xj[r][c4+0] = fb.x - mJ.x; xj[r][c4+1] = fb.y - mJ.y;
    xj[r][c4+2] = fb.z - mJ.z; xj[r][c4+3] = fb.w - mJ.w;
    __syncthreads();
    #pragma unroll
    for (int t = 0; t < 16; ++t) {
      float4 qa = *(const float4*)&xi[t][i4];
      float4 qb = *(const float4*)&xj[t][j4];
      acc[0][0] = fmaf(qa.x, qb.x, acc[0][0]); acc[0][1] = fmaf(qa.x, qb.y, acc[0][1]);
      acc[0][2] = fmaf(qa.x, qb.z, acc[0][2]); acc[0][3] = fmaf(qa.x, qb.w, acc[0][3]);
      acc[1][0] = fmaf(qa.y, qb.x, acc[1][0]); acc[1][1] = fmaf(qa.y, qb.y, acc[1][1]);
      acc[1][2] = fmaf(qa.y, qb.z, acc[1][2]); acc[1][3] = fmaf(qa.y, qb.w, acc[1][3]);
      acc[2][0] = fmaf(qa.z, qb.x, acc[2][0]); acc[2][1] = fmaf(qa.z, qb.y, acc[2][1]);
      acc[2][2] = fmaf(qa.z, qb.z, acc[2][2]); acc[2][3] = fmaf(qa.z, qb.w, acc[2][3]);
      acc[3][0] = fmaf(qa.w, qb.x, acc[3][0]); acc[3][1] = fmaf(qa.w, qb.y, acc[3][1]);
      acc[3][2] = fmaf(qa.w, qb.z, acc[3][2]); acc[3][3] = fmaf(qa.w, qb.w, acc[3][3]);
    }
  }
  const float inv = 1.0f / (float)(T_ - 1);
  float* out = Sg + (size_t)b*D_*D_;
  #pragma unroll
  for (int ii = 0; ii < 4; ++ii)
    #pragma unroll
    for (int jj = 0; jj < 4; ++jj) {
      int row = I0 + i4 + ii, col = J0 + j4 + jj;
      float v = acc[ii][jj] * inv;
      if (row == col) v += 1e-6f;
      out[(size_t)row*D_ + col] = v;
    }
}

// ---------------- blocked Cholesky ----------------
#define CNB 32

__global__ __launch_bounds__(256) void chol_k(float* __restrict__ SA, float* __restrict__ SV) {
  float* M = (blockIdx.y ? SV : SA) + (size_t)blockIdx.x * D_ * D_;
  __shared__ float SB[CNB][36];
  __shared__ float PDiag[CNB][36];
  __shared__ float PL[CNB][36];
  __shared__ float PDinv[CNB];

  const int tid = threadIdx.x;
  const int r0i = 2 * tid;
  float* row0 = M + (size_t)r0i * D_;
  float* row1 = row0 + D_;

  for (int J = 0; J < D_; J += CNB) {
    const bool own = (tid < 128) && (r0i >= J);
    const bool diagown = own && (r0i < J + CNB);
    float acc0[CNB], acc1[CNB];
    if (own) {
      #pragma unroll
      for (int q = 0; q < CNB; q += 4) {
        float4 f0 = *(const float4*)(row0 + J + q);
        acc0[q]=f0.x; acc0[q+1]=f0.y; acc0[q+2]=f0.z; acc0[q+3]=f0.w;
        float4 f1 = *(const float4*)(row1 + J + q);
        acc1[q]=f1.x; acc1[q+1]=f1.y; acc1[q+2]=f1.z; acc1[q+3]=f1.w;
      }
    }
    for (int k0 = 0; k0 < J; k0 += 32) {
      __syncthreads();
      {
        int jj = tid >> 3, c = (tid & 7) * 4;
        float4 f = *(const float4*)(M + (size_t)(J + jj) * D_ + k0 + c);
        *(float4*)&SB[jj][c] = f;
      }
      __syncthreads();
      if (own) {
        float lv0[32], lv1[32];
        #pragma unroll
        for (int q = 0; q < 32; q += 4) {
          float4 f0 = *(const float4*)(row0 + k0 + q);
          lv0[q]=f0.x; lv0[q+1]=f0.y; lv0[q+2]=f0.z; lv0[q+3]=f0.w;
          float4 f1 = *(const float4*)(row1 + k0 + q);
          lv1[q]=f1.x; lv1[q+1]=f1.y; lv1[q+2]=f1.z; lv1[q+3]=f1.w;
        }
        #pragma unroll
        for (int jj = 0; jj < CNB; ++jj) {
          float s0 = 0.f, s1 = 0.f;
          #pragma unroll
          for (int c = 0; c < 32; c += 4) {
            float4 b = *(const float4*)&SB[jj][c];
            s0 = fmaf(lv0[c],   b.x, s0); s0 = fmaf(lv0[c+1], b.y, s0);
            s0 = fmaf(lv0[c+2], b.z, s0); s0 = fmaf(lv0[c+3], b.w, s0);
            s1 = fmaf(lv1[c],   b.x, s1); s1 = fmaf(lv1[c+1], b.y, s1);
            s1 = fmaf(lv1[c+2], b.z, s1); s1 = fmaf(lv1[c+3], b.w, s1);
          }
          acc0[jj] -= s0; acc1[jj] -= s1;
        }
      }
    }
    __syncthreads();
    if (diagown) {
      int dr = r0i - J;
      #pragma unroll
      for (int q = 0; q < CNB; q += 4) {
        *(float4*)&PDiag[dr][q]   = make_float4(acc0[q], acc0[q+1], acc0[q+2], acc0[q+3]);
        *(float4*)&PDiag[dr+1][q] = make_float4(acc1[q], acc1[q+1], acc1[q+2], acc1[q+3]);
      }
    }
    __syncthreads();
    if (tid < 32) {
      const int r = tid;
      float a[CNB];
      #pragma unroll
      for (int q = 0; q < CNB; q += 4) {
        float4 f = *(const float4*)&PDiag[r][q];
        a[q]=f.x; a[q+1]=f.y; a[q+2]=f.z; a[q+3]=f.w;
      }
      #pragma unroll
      for (int j = 0; j < CNB; ++j) {
        float ajj = __shfl(a[j], j);
        float d = sqrtf(ajj);
        float dinv = 1.0f / d;
        float lcol = (r == j) ? d : a[j] * dinv;
        a[j] = lcol;
        if (r == j) PDinv[j] = dinv;
        #pragma unroll
        for (int k = j + 1; k < CNB; ++k) {
          float lkj = __shfl(lcol, k);
          a[k] = fmaf(-lcol, lkj, a[k]);
        }
      }
      #pragma unroll
      for (int q = 0; q < CNB; q += 4) {
        float4 o;
        o.x = (q   < r) ? a[q]   : 0.f;
        o.y = (q+1 < r) ? a[q+1] : 0.f;
        o.z = (q+2 < r) ? a[q+2] : 0.f;
        o.w = (q+3 < r) ? a[q+3] : 0.f;
        *(float4*)&PL[r][q] = o;
      }
      float* grow = M + (size_t)(J + r) * D_ + J;
      #pragma unroll
      for (int q = 0; q < CNB; q += 4) {
        float4 o;
        o.x = (q   <= r) ? a[q]   : 0.f;
        o.y = (q+1 <= r) ? a[q+1] : 0.f;
        o.z = (q+2 <= r) ? a[q+2] : 0.f;
        o.w = (q+3 <= r) ? a[q+3] : 0.f;
        *(float4*)(grow + q) = o;
      }
    }
    __syncthreads();
    if (own && !diagown) {
      #pragma unroll
      for (int j = 0; j < CNB; ++j) {
        float s0 = 0.f, s1 = 0.f;
        const int cq = (j + 3) >> 2;
        #pragma unroll
        for (int c = 0; c < 8; ++c) {
          if (c < cq) {
            float4 b = *(const float4*)&PL[j][c*4];
            s0 = fmaf(acc0[c*4],   b.x, s0); s0 = fmaf(acc0[c*4+1], b.y, s0);
            s0 = fmaf(acc0[c*4+2], b.z, s0); s0 = fmaf(acc0[c*4+3], b.w, s0);
            s1 = fmaf(acc1[c*4],   b.x, s1); s1 = fmaf(acc1[c*4+1], b.y, s1);
            s1 = fmaf(acc1[c*4+2], b.z, s1); s1 = fmaf(acc1[c*4+3], b.w, s1);
          }
        }
        float di = PDinv[j];
        acc0[j] = (acc0[j] - s0) * di;
        acc1[j] = (acc1[j] - s1) * di;
      }
      #pragma unroll
      for (int q = 0; q < CNB; q += 4) {
        *(float4*)(row0 + J + q) = make_float4(acc0[q], acc0[q+1], acc0[q+2], acc0[q+3]);
        *(float4*)(row1 + J + q) = make_float4(acc1[q], acc1[q+1], acc1[q+2], acc1[q+3]);
      }
    }
    __syncthreads();
  }
  // vectorized upper-triangle zeroing: row tid, cols tid+1..255
  {
    float* rowt = M + (size_t)tid * D_;
    int k = tid + 1;
    while (k < D_ && (k & 3)) rowt[k++] = 0.f;
    const float4 z4 = make_float4(0.f, 0.f, 0.f, 0.f);
    for (; k < D_; k += 4) *(float4*)(rowt + k) = z4;
  }
}

// ---------------- transpose A,V (f32 [b][t][d]) -> bf16 [b][d][T] ----------------
__global__ __launch_bounds__(256) void trans_k(const float* __restrict__ A,
    const float* __restrict__ V, __bf16* __restrict__ At, __bf16* __restrict__ Vt) {
  const float* X = blockIdx.z ? V : A;
  __bf16* Xt = blockIdx.z ? Vt : At;
  int b = blockIdx.y, t0 = blockIdx.x * 64, tid = threadIdx.x;
  __shared__ __bf16 TT[64 * 264];
  #pragma unroll
  for (int it = 0; it < 16; ++it) {
    int flat = it*1024 + tid*4;
    int t = flat >> 8, c = flat & 255;
    float4 f = *(const float4*)(X + ((size_t)b*T_ + t0 + t)*D_ + c);
    bf16x4 u;
    u[0] = (__bf16)f.x; u[1] = (__bf16)f.y; u[2] = (__bf16)f.z; u[3] = (__bf16)f.w;
    *(bf16x4*)&TT[t*264 + c] = u;
  }
  __syncthreads();
  int d = tid;
  __bf16* orow = Xt + ((size_t)b*D_ + d)*T_ + t0;
  #pragma unroll
  for (int g = 0; g < 8; ++g) {
    bf16x8 o;
    #pragma unroll
    for (int j = 0; j < 8; ++j) o[j] = TT[(g*8 + j)*264 + d];
    *(bf16x8*)(orow + g*8) = o;
  }
}

// ---------------- K16 = bf16(mu + eps @ L^T), register-tiled, eps/L staged [dd][*] ----------------
__global__ __launch_bounds__(256) void kgen_k(const float* __restrict__ L,
    const float* __restrict__ mu, __bf16* __restrict__ Kout, uint32_t key) {
  __shared__ float eps_s[16 * 64];    // [dd][t]
  __shared__ float L_s[16 * 256];     // [dd][e]
  const int b  = blockIdx.y;
  const int t0 = blockIdx.x * 64;
  const int tid = threadIdx.x;
  const int tt = tid >> 4;            // 0..15
  const int te = tid & 15;            // 0..15
  const int tg = tid & 63;            // eps-gen t
  const int dg = (tid >> 6) * 4;      // eps-gen dd base
  float acc[4][16];
  #pragma unroll
  for (int eq = 0; eq < 4; ++eq)
    #pragma unroll
    for (int i = 0; i < 16; ++i) acc[eq][i] = 0.f;

  for (int d0 = 0; d0 < D_; d0 += 16) {
    __syncthreads();
    uint32_t nbase = ((uint32_t)(b*T_ + t0 + tg))*256u + (uint32_t)(d0 + dg);
    #pragma unroll
    for (int q = 0; q < 4; ++q)
      eps_s[(dg + q)*64 + tg] = jax_normal_elem(key, nbase + q);
    {
      const float* lrow = L + (size_t)b*D_*D_ + (size_t)tid*D_ + d0;
      #pragma unroll
      for (int q = 0; q < 4; ++q) {
        float4 f = *(const float4*)(lrow + q*4);
        L_s[(q*4+0)*256 + tid] = f.x;
        L_s[(q*4+1)*256 + tid] = f.y;
        L_s[(q*4+2)*256 + tid] = f.z;
        L_s[(q*4+3)*256 + tid] = f.w;
      }
    }
    __syncthreads();
    #pragma unroll
    for (int dd = 0; dd < 16; ++dd) {
      float4 ep = *(const float4*)&eps_s[dd*64 + 4*tt];
      #pragma unroll
      for (int eq = 0; eq < 4; ++eq) {
        float4 lf = *(const float4*)&L_s[dd*256 + eq*64 + 4*te];
        acc[eq][0]  = fmaf(ep.x, lf.x, acc[eq][0]);  acc[eq][1]  = fmaf(ep.x, lf.y, acc[eq][1]);
        acc[eq][2]  = fmaf(ep.x, lf.z, acc[eq][2]);  acc[eq][3]  = fmaf(ep.x, lf.w, acc[eq][3]);
        acc[eq][4]  = fmaf(ep.y, lf.x, acc[eq][4]);  acc[eq][5]  = fmaf(ep.y, lf.y, acc[eq][5]);
        acc[eq][6]  = fmaf(ep.y, lf.z, acc[eq][6]);  acc[eq][7]  = fmaf(ep.y, lf.w, acc[eq][7]);
        acc[eq][8]  = fmaf(ep.z, lf.x, acc[eq][8]);  acc[eq][9]  = fmaf(ep.z, lf.y, acc[eq][9]);
        acc[eq][10] = fmaf(ep.z, lf.z, acc[eq][10]); acc[eq][11] = fmaf(ep.z, lf.w, acc[eq][11]);
        acc[eq][12] = fmaf(ep.w, lf.x, acc[eq][12]); acc[eq][13] = fmaf(ep.w, lf.y, acc[eq][13]);
        acc[eq][14] = fmaf(ep.w, lf.z, acc[eq][14]); acc[eq][15] = fmaf(ep.w, lf.w, acc[eq][15]);
      }
    }
  }
  #pragma unroll
  for (int eq = 0; eq < 4; ++eq) {
    float4 m4 = *(const float4*)(mu + b*D_ + eq*64 + 4*te);
    #pragma unroll
    for (int i = 0; i < 4; ++i) {
      bf16x4 o;
      o[0] = (__bf16)(acc[eq][i*4+0] + m4.x);
      o[1] = (__bf16)(acc[eq][i*4+1] + m4.y);
      o[2] = (__bf16)(acc[eq][i*4+2] + m4.z);
      o[3] = (__bf16)(acc[eq][i*4+3] + m4.w);
      *(bf16x4*)(Kout + ((size_t)b*T_ + t0 + 4*tt + i)*D_ + eq*64 + 4*te) = o;
    }
  }
}

// ---------------- MFMA flash attention, all-bf16 staged: O = softmax(Q K^T / 16) V ----------------
#define SCALE_ 0.0625f
#define KSTR 264
#define VSTR 72
#define SFSTR 68
#define PSTR 72

__global__ __launch_bounds__(256, 2) void attn_mfma(const float* __restrict__ Qg,
    const __bf16* __restrict__ K16, const __bf16* __restrict__ Vt,
    __bf16* __restrict__ Og) {
  // LDS: [KS 33792 | Sf 17408 overlay] + VS 36864 + Ps 9216 + rowm/l/a 768 = 80640 B (2 blocks/CU)
  __shared__ __align__(16) char smem[80640];
  __bf16* KS = (__bf16*)smem;                      // [64][KSTR]
  float*  Sf = (float*)smem;                       // [64][SFSTR] (overlays KS)
  __bf16* VS = (__bf16*)(smem + 33792);            // [256][VSTR]
  __bf16* Ps = (__bf16*)(smem + 33792 + 36864);    // [64][PSTR]
  float* rowm = (float*)(smem + 33792 + 36864 + 9216);
  float* rowl = rowm + 64;
  float* rowa = rowm + 128;

  const int tid  = threadIdx.x;
  const int wv   = tid >> 6;
  const int lane = tid & 63;
  const int ln31 = lane & 31;
  const int h8   = (lane >> 5) * 8;
  const int qb   = (wv >> 1) * 32;
  const int sb   = (wv & 1) * 32;
  const int cb   = (wv & 1) * 128;
  // XCD-swizzle: each XCD (bid%8) works 2 batches -> K+V working set ~4MB = L2
  const int flat = blockIdx.x;
  const int b    = ((flat & 7) << 1) | ((flat >> 3) & 1);
  const int t0   = (flat >> 4) * 64;

  // Q -> registers as bf16 A-frags
  bf16x8 qf[16];
  {
    const float* qrow = Qg + ((size_t)b*T_ + t0 + qb + ln31) * D_;
    #pragma unroll
    for (int s = 0; s < 16; ++s) {
      float4 f0 = *(const float4*)(qrow + s*16 + h8);
      float4 f1 = *(const float4*)(qrow + s*16 + h8 + 4);
      bf16x8 q;
      q[0] = (__bf16)f0.x; q[1] = (__bf16)f0.y; q[2] = (__bf16)f0.z; q[3] = (__bf16)f0.w;
      q[4] = (__bf16)f1.x; q[5] = (__bf16)f1.y; q[6] = (__bf16)f1.z; q[7] = (__bf16)f1.w;
      qf[s] = q;
    }
  }
  if (tid < 64) { rowm[tid] = -INFINITY; rowl[tid] = 0.f; }

  float16 oacc[4];
  #pragma unroll
  for (int nb = 0; nb < 4; ++nb)
    #pragma unroll
    for (int i = 0; i < 16; ++i) oacc[nb][i] = 0.f;

  for (int s0 = 0; s0 < T_; s0 += 64) {
    __syncthreads();   // (1) prev-tile VS/Ps reads done; KS region reuse
    // ---- stage K tile: dense b128 moves (r = fl>>5: 64 rows x 32 chunks of 8) ----
    #pragma unroll
    for (int it = 0; it < 8; ++it) {
      int fl = it*256 + tid;
      int r = fl >> 5, c8 = (fl & 31) * 8;
      *(bf16x8*)&KS[r*KSTR + c8] =
          *(const bf16x8*)(K16 + ((size_t)b*T_ + s0 + r)*D_ + c8);
    }
    // ---- stage V tile from transposed Vt: dense b128 moves ----
    #pragma unroll
    for (int it = 0; it < 8; ++it) {
      int fl = it*256 + tid;
      int d = fl >> 3, sc = (fl & 7) * 8;
      *(bf16x8*)&VS[d*VSTR + sc] =
          *(const bf16x8*)(Vt + ((size_t)b*D_ + d)*T_ + s0 + sc);
    }
    __syncthreads();   // (2)
    // ---- S = Q K^T ----
    float16 sacc = {0.f,0.f,0.f,0.f,0.f,0.f,0.f,0.f,0.f,0.f,0.f,0.f,0.f,0.f,0.f,0.f};
    #pragma unroll
    for (int d = 0; d < 16; ++d) {
      bf16x8 kf = *(const bf16x8*)&KS[(sb + ln31)*KSTR + d*16 + h8];
      sacc = __builtin_amdgcn_mfma_f32_32x32x16_bf16(qf[d], kf, sacc, 0, 0, 0);
    }
    __syncthreads();   // (3) KS reads complete before Sf overlay write
    #pragma unroll
    for (int r = 0; r < 16; ++r) {
      int row = qb + (r & 3) + 8*(r >> 2) + 4*(lane >> 5);
      Sf[row*SFSTR + sb + ln31] = sacc[r] * SCALE_;
    }
    __syncthreads();   // (4)
    // ---- online softmax: 4 threads per row ----
    {
      int r = tid >> 2, sub = tid & 3;
      const float* srow = &Sf[r*SFSTR + sub*16];
      float4 a0 = *(const float4*)(srow);
      float4 a1 = *(const float4*)(srow + 4);
      float4 a2 = *(const float4*)(srow + 8);
      float4 a3 = *(const float4*)(srow + 12);
      float xv[16] = {a0.x,a0.y,a0.z,a0.w, a1.x,a1.y,a1.z,a1.w,
                      a2.x,a2.y,a2.z,a2.w, a3.x,a3.y,a3.z,a3.w};
      float mloc = xv[0];
      #pragma unroll
      for (int i = 1; i < 16; ++i) mloc = fmaxf(mloc, xv[i]);
      mloc = fmaxf(mloc, __shfl_xor(mloc, 1));
      mloc = fmaxf(mloc, __shfl_xor(mloc, 2));
      float mold = rowm[r];
      float mnew = fmaxf(mold, mloc);
      float ls = 0.f;
      #pragma unroll
      for (int i = 0; i < 16; ++i) { xv[i] = expf(xv[i] - mnew); ls += xv[i]; }
      #pragma unroll
      for (int i = 0; i < 8; ++i) {
        bf16x2 t2; t2[0] = (__bf16)xv[2*i]; t2[1] = (__bf16)xv[2*i+1];
        *(bf16x2*)&Ps[r*PSTR + sub*16 + 2*i] = t2;
      }
      ls += __shfl_xor(ls, 1);
      ls += __shfl_xor(ls, 2);
      if (sub == 0) {
        float al = expf(mold - mnew);
        rowa[r] = al;
        rowl[r] = rowl[r] * al + ls;
        rowm[r] = mnew;
      }
    }
    __syncthreads();   // (5)
    #pragma unroll
    for (int r = 0; r < 16; ++r) {
      float al = rowa[qb + (r & 3) + 8*(r >> 2) + 4*(lane >> 5)];
      oacc[0][r] *= al; oacc[1][r] *= al; oacc[2][r] *= al; oacc[3][r] *= al;
    }
    // ---- O += P V (P and V both from LDS) ----
    #pragma unroll
    for (int ks = 0; ks < 4; ++ks) {
      bf16x8 pf = *(const bf16x8*)&Ps[(qb + ln31)*PSTR + ks*16 + h8];
      #pragma unroll
      for (int nb = 0; nb < 4; ++nb) {
        bf16x8 vf = *(const bf16x8*)&VS[(cb + nb*32 + ln31)*VSTR + ks*16 + h8];
        oacc[nb] = __builtin_amdgcn_mfma_f32_32x32x16_bf16(pf, vf, oacc[nb], 0, 0, 0);
      }
    }
  }
  // ---- epilogue: O /= l, store bf16 ----
  #pragma unroll
  for (int r = 0; r < 16; ++r) {
    int row = qb + (r & 3) + 8*(r >> 2) + 4*(lane >> 5);
    float inv = 1.0f / rowl[row];
    __bf16* orow = Og + ((size_t)b*T_ + t0 + row)*D_ + cb + ln31;
    orow[0]  = (__bf16)(oacc[0][r] * inv);
    orow[32] = (__bf16)(oacc[1][r] * inv);
    orow[64] = (__bf16)(oacc[2][r] * inv);
    orow[96] = (__bf16)(oacc[3][r] * inv);
  }
}

// ---------------- gates + cosine combine (att inputs bf16) ----------------
__global__ __launch_bounds__(256) void comb_k(const float* __restrict__ A,
    const float* __restrict__ Vv, const __bf16* __restrict__ att1,
    const __bf16* __restrict__ att2, const float* __restrict__ WA,
    const float* __restrict__ WV, const float* __restrict__ bA,
    const float* __restrict__ bV, float* __restrict__ out) {
  int wv = threadIdx.x >> 6;
  int lane = threadIdx.x & 63;
  size_t row = (size_t)blockIdx.x * 4 + wv;
  size_t base = row * D_;
  int d = lane * 4;
  float4 a  = *(const float4*)(A + base + d);
  float4 v  = *(const float4*)(Vv + base + d);
  bf16x4 xb = *(const bf16x4*)(att1 + base + d);
  bf16x4 yb = *(const bf16x4*)(att2 + base + d);
  float4 x = make_float4((float)xb[0], (float)xb[1], (float)xb[2], (float)xb[3]);
  float4 y = make_float4((float)yb[0], (float)yb[1], (float)yb[2], (float)yb[3]);
  float4 w1 = *(const float4*)(WA + d);
  float4 w2 = *(const float4*)(WA + 256 + d);
  float4 w3 = *(const float4*)(WV + d);
  float4 w4 = *(const float4*)(WV + 256 + d);
  float sga = a.x*w1.x + a.y*w1.y + a.z*w1.z + a.w*w1.w
            + x.x*w2.x + x.y*w2.y + x.z*w2.z + x.w*w2.w;
  float sgv = v.x*w3.x + v.y*w3.y + v.z*w3.z + v.w*w3.w
            + y.x*w4.x + y.y*w4.y + y.z*w4.z + y.w*w4.w;
  float sav = a.x*v.x + a.y*v.y + a.z*v.z + a.w*v.w;
  float saa = a.x*a.x + a.y*a.y + a.z*a.z + a.w*a.w;
  float svv = v.x*v.x + v.y*v.y + v.z*v.z + v.w*v.w;
  #pragma unroll
  for (int m = 32; m; m >>= 1) {
    sga += __shfl_xor(sga, m);
    sgv += __shfl_xor(sgv, m);
    sav += __shfl_xor(sav, m);
    saa += __shfl_xor(saa, m);
    svv += __shfl_xor(svv, m);
  }
  float gA = 1.0f / (1.0f + expf(-(sga + bA[0])));
  float gV = 1.0f / (1.0f + expf(-(sgv + bV[0])));
  float cs = sav / fmaxf(sqrtf(saa) * sqrtf(svv), 1e-8f);
  float al = 1.0f / (1.0f + expf(-cs));
  float be = 1.0f - al;
  float4 o;
  o.x = al * (gA*a.x + (1.0f-gA)*x.x) + be * (gV*v.x + (1.0f-gV)*y.x);
  o.y = al * (gA*a.y + (1.0f-gA)*x.y) + be * (gV*v.y + (1.0f-gV)*y.y);
  o.z = al * (gA*a.z + (1.0f-gA)*x.z) + be * (gV*v.z + (1.0f-gV)*y.z);
  o.w = al * (gA*a.w + (1.0f-gA)*x.w) + be * (gV*v.w + (1.0f-gV)*y.w);
  *(float4*)(out + base + d) = o;
}

extern "C" void kernel_launch(void* const* d_in, const int* in_sizes, int n_in,
                              void* d_out, int out_size, void* d_ws, size_t ws_size,
                              hipStream_t stream) {
  (void)in_sizes; (void)n_in; (void)out_size; (void)ws_size;
  const float* A  = (const float*)d_in[0];
  const float* V  = (const float*)d_in[1];
  const float* WA = (const float*)d_in[2];
  const float* WV = (const float*)d_in[3];
  const float* bA = (const float*)d_in[4];
  const float* bV = (const float*)d_in[5];
  float* ws  = (float*)d_ws;
  float*  muA  = ws;                                   // 4096 f
  float*  muV  = muA + 4096;                           // 4096 f
  float*  LA   = muV + 4096;                           // 1,048,576 f
  float*  LV   = LA + (size_t)B_*D_*D_;                // 1,048,576 f
  __bf16* K16  = (__bf16*)(LV + (size_t)B_*D_*D_);     // N_ bf16 (N_/2 f-slots)
  __bf16* At16 = (__bf16*)((float*)K16 + N_/2);        // N_ bf16
  __bf16* Vt16 = (__bf16*)((float*)At16 + N_/2);       // N_ bf16
  __bf16* at1  = (__bf16*)((float*)Vt16 + N_/2);       // N_ bf16
  __bf16* at2  = (__bf16*)((float*)at1 + N_/2);        // N_ bf16
  // total ~23.1M float-slots = ~92 MB

  mean_k<<<dim3(16,2), dim3(1024), 0, stream>>>(A, V, muA, muV);
  sigma_k<<<dim3(10,16,2), dim3(256), 0, stream>>>(A, V, muA, muV, LA, LV);
  chol_k<<<dim3(16,2), dim3(256), 0, stream>>>(LA, LV);
  trans_k<<<dim3(32,16,2), dim3(256), 0, stream>>>(A, V, At16, Vt16);
  // K_v = resample(V, key 42): audio queries attend to it, values = V
  kgen_k<<<dim3(32,16), dim3(256), 0, stream>>>(LV, muV, K16, 42u);
  attn_mfma<<<dim3(512), dim3(256), 0, stream>>>(A, K16, Vt16, at1);
  // K_a = resample(A, key 43): visual queries attend to it, values = A
  kgen_k<<<dim3(32,16), dim3(256), 0, stream>>>(LA, muA, K16, 43u);
  attn_mfma<<<dim3(512), dim3(256), 0, stream>>>(V, K16, At16, at2);
  comb_k<<<dim3(8192), dim3(256), 0, stream>>>(A, V, at1, at2, WA, WV, bA, bV, (float*)d_out);
}

// Round 7
// 1194.384 us; speedup vs baseline: 1.1836x; 1.0954x over previous
//
#include <hip/hip_runtime.h>
#include <stdint.h>
#include <math.h>

#define B_ 16
#define T_ 2048
#define D_ 256
#define N_ (B_*T_*D_)   // 8388608

typedef __attribute__((ext_vector_type(8)))  __bf16 bf16x8;
typedef __attribute__((ext_vector_type(4)))  __bf16 bf16x4;
typedef __attribute__((ext_vector_type(2)))  __bf16 bf16x2;
typedef __attribute__((ext_vector_type(16))) float  float16;

// ---------------- JAX threefry2x32 (partitionable layout) ----------------
__device__ __forceinline__ uint32_t rotl32(uint32_t v, int r) {
  return (v << r) | (v >> (32 - r));
}

__device__ __forceinline__ void threefry2x32(uint32_t k0, uint32_t k1,
                                             uint32_t x0, uint32_t x1,
                                             uint32_t& o0, uint32_t& o1) {
  uint32_t ks2 = k0 ^ k1 ^ 0x1BD11BDAu;
#define TF_ROUND(r) { x0 += x1; x1 = rotl32(x1, r); x1 ^= x0; }
  x0 += k0; x1 += k1;
  TF_ROUND(13) TF_ROUND(15) TF_ROUND(26) TF_ROUND(6)
  x0 += k1; x1 += ks2 + 1u;
  TF_ROUND(17) TF_ROUND(29) TF_ROUND(16) TF_ROUND(24)
  x0 += ks2; x1 += k0 + 2u;
  TF_ROUND(13) TF_ROUND(15) TF_ROUND(26) TF_ROUND(6)
  x0 += k0; x1 += k1 + 3u;
  TF_ROUND(17) TF_ROUND(29) TF_ROUND(16) TF_ROUND(24)
  x0 += k1; x1 += ks2 + 4u;
  TF_ROUND(13) TF_ROUND(15) TF_ROUND(26) TF_ROUND(6)
  x0 += ks2; x1 += k0 + 5u;
#undef TF_ROUND
  o0 = x0; o1 = x1;
}

// XLA ErfInv f32 polynomial (Giles)
__device__ __forceinline__ float erfinv_xla(float x) {
  float w = -log1pf(-x * x);
  float p;
  if (w < 5.0f) {
    w -= 2.5f;
    p = 2.81022636e-08f;
    p = fmaf(p, w, 3.43273939e-07f);
    p = fmaf(p, w, -3.5233877e-06f);
    p = fmaf(p, w, -4.39150654e-06f);
    p = fmaf(p, w, 0.00021858087f);
    p = fmaf(p, w, -0.00125372503f);
    p = fmaf(p, w, -0.00417768164f);
    p = fmaf(p, w, 0.246640727f);
    p = fmaf(p, w, 1.50140941f);
  } else {
    w = sqrtf(w) - 3.0f;
    p = -0.000200214257f;
    p = fmaf(p, w, 0.000100950558f);
    p = fmaf(p, w, 0.00134934322f);
    p = fmaf(p, w, -0.00367342844f);
    p = fmaf(p, w, 0.00573950773f);
    p = fmaf(p, w, -0.0076224613f);
    p = fmaf(p, w, 0.00943887047f);
    p = fmaf(p, w, 1.00167406f);
    p = fmaf(p, w, 2.83297682f);
  }
  return p * x;
}

// jax.random.normal element n (flat row-major index), key=(0, seed)
__device__ __forceinline__ float jax_normal_elem(uint32_t key, uint32_t n) {
  uint32_t o0, o1;
  threefry2x32(0u, key, 0u, n, o0, o1);
  uint32_t bits = o0 ^ o1;                     // partitionable 32-bit output
  float f = __uint_as_float((bits >> 9) | 0x3f800000u) - 1.0f;  // [0,1)
  const float lo = -0.99999994f;               // nextafter(-1,0)
  float u = fmaxf(lo, fmaf(f, 2.0f, lo));      // (maxval-minval) rounds to 2.0f
  return 1.41421356f * erfinv_xla(u);          // sqrt(2) in f32
}

// ---------------- mean over T ----------------
__global__ __launch_bounds__(1024) void mean_k(const float* __restrict__ A,
    const float* __restrict__ Vv, float* __restrict__ muA, float* __restrict__ muV) {
  const float* X = blockIdx.y ? Vv : A;
  float* mu = blockIdx.y ? muV : muA;
  int b = blockIdx.x;
  int d = threadIdx.x & 255;
  int part = threadIdx.x >> 8;   // 0..3
  __shared__ float partial[4][256];
  const float* p = X + ((size_t)b*T_ + (size_t)part*(T_/4))*D_ + d;
  float s = 0.f;
  for (int t = 0; t < T_/4; ++t) s += p[(size_t)t * D_];
  partial[part][d] = s;
  __syncthreads();
  if (part == 0)
    mu[b*D_ + d] = (partial[0][d] + partial[1][d] + partial[2][d] + partial[3][d]) * (1.0f/(float)T_);
}

// ---------------- Sigma = Xc^T Xc / (T-1), lower tiles only, +jitter on diag ----------------
__global__ __launch_bounds__(256) void sigma_k(const float* __restrict__ A,
    const float* __restrict__ Vv, const float* __restrict__ muA,
    const float* __restrict__ muV, float* __restrict__ SA, float* __restrict__ SV) {
  const float* X  = blockIdx.z ? Vv  : A;
  const float* mu = blockIdx.z ? muV : muA;
  float* Sg       = blockIdx.z ? SV  : SA;
  const int TIa[10] = {0,1,1,2,2,2,3,3,3,3};
  const int TJa[10] = {0,0,1,0,1,2,0,1,2,3};
  int b = blockIdx.y;
  int I0 = TIa[blockIdx.x]*64, J0 = TJa[blockIdx.x]*64;
  __shared__ float xi[16][64];
  __shared__ float xj[16][64];
  int tid = threadIdx.x;
  int r = tid >> 4, c4 = (tid & 15) * 4;
  float4 mI = *(const float4*)(mu + b*D_ + I0 + c4);
  float4 mJ = *(const float4*)(mu + b*D_ + J0 + c4);
  float acc[4][4] = {};
  int i4 = (tid >> 4) * 4, j4 = (tid & 15) * 4;
  for (int t0 = 0; t0 < T_; t0 += 16) {
    __syncthreads();
    const float* px = X + ((size_t)b*T_ + t0 + r) * D_;
    float4 fa = *(const float4*)(px + I0 + c4);
    xi[r][c4+0] = fa.x - mI.x; xi[r][c4+1] = fa.y - mI.y;
    xi[r][c4+2] = fa.z - mI.z; xi[r][c4+3] = fa.w - mI.w;
    float4 fb = *(const float4*)(px + J0 + c4);
    xj[r][c4+0] = fb.x - mJ.x; xj[r][c4+1] = fb.y - mJ.y;
    xj[r][c4+2] = fb.z - mJ.z; xj[r][c4+3] = fb.w - mJ.w;
    __syncthreads();
    #pragma unroll
    for (int t = 0; t < 16; ++t) {
      float4 qa = *(const float4*)&xi[t][i4];
      float4 qb = *(const float4*)&xj[t][j4];
      acc[0][0] = fmaf(qa.x, qb.x, acc[0][0]); acc[0][1] = fmaf(qa.x, qb.y, acc[0][1]);
      acc[0][2] = fmaf(qa.x, qb.z, acc[0][2]); acc[0][3] = fmaf(qa.x, qb.w, acc[0][3]);
      acc[1][0] = fmaf(qa.y, qb.x, acc[1][0]); acc[1][1] = fmaf(qa.y, qb.y, acc[1][1]);
      acc[1][2] = fmaf(qa.y, qb.z, acc[1][2]); acc[1][3] = fmaf(qa.y, qb.w, acc[1][3]);
      acc[2][0] = fmaf(qa.z, qb.x, acc[2][0]); acc[2][1] = fmaf(qa.z, qb.y, acc[2][1]);
      acc[2][2] = fmaf(qa.z, qb.z, acc[2][2]); acc[2][3] = fmaf(qa.z, qb.w, acc[2][3]);
      acc[3][0] = fmaf(qa.w, qb.x, acc[3][0]); acc[3][1] = fmaf(qa.w, qb.y, acc[3][1]);
      acc[3][2] = fmaf(qa.w, qb.z, acc[3][2]); acc[3][3] = fmaf(qa.w, qb.w, acc[3][3]);
    }
  }
  const float inv = 1.0f / (float)(T_ - 1);
  float* out = Sg + (size_t)b*D_*D_;
  #pragma unroll
  for (int ii = 0; ii < 4; ++ii)
    #pragma unroll
    for (int jj = 0; jj < 4; ++jj) {
      int row = I0 + i4 + ii, col = J0 + j4 + jj;
      float v = acc[ii][jj] * inv;
      if (row == col) v += 1e-6f;
      out[(size_t)row*D_ + col] = v;
    }
}

// ---------------- blocked Cholesky v3: 8x4 register-tiled Schur update ----------------
// LDS-instr diet: GEMM B-reads 32 b128/thread/chunk (was 256); TRSM right-looking with
// transposed PLT rows = wave-uniform broadcast reads. One block per (batch, modality).
#define CNB 32

__global__ __launch_bounds__(256) void chol_k(float* __restrict__ SA, float* __restrict__ SV) {
  float* M = (blockIdx.y ? SV : SA) + (size_t)blockIdx.x * D_ * D_;
  __shared__ float Pbuf[256][36];    // updated panel cols [J..J+32) for rows 0..255 (36 KB)
  __shared__ float SB[CNB][36];      // staged B chunk: SB[c][k] = L[J+c][k0+k]
  __shared__ float PLT[CNB][36];     // PLT[j][k] = L[J+k][J+j] for k>j, else 0
  __shared__ float PDinv[CNB];

  const int tid = threadIdx.x;
  const int tr  = tid >> 3;          // row-group 0..31 (8 rows each)
  const int tc  = tid & 7;           // col set {tc, tc+8, tc+16, tc+24} (bank-spread)
  const int gi0 = tr * 8;

  for (int J = 0; J < D_; J += CNB) {
    __syncthreads();
    // ---- stage panel columns into Pbuf (original Sigma values, cols >= J untouched) ----
    {
      const int nq = (D_ - J) * 8;
      for (int fl = tid; fl < nq; fl += 256) {
        int r = J + (fl >> 3), q = (fl & 7) * 4;
        *(float4*)&Pbuf[r][q] = *(const float4*)(M + (size_t)r * D_ + J + q);
      }
    }
    // ---- GEMM: acc[r][o] = sum_{k<J} L[gi0+r][k] * L[J+tc+8o][k] ----
    const bool gact = (gi0 >= J);
    float acc[8][4];
    #pragma unroll
    for (int r = 0; r < 8; ++r)
      #pragma unroll
      for (int o = 0; o < 4; ++o) acc[r][o] = 0.f;
    for (int k0 = 0; k0 < J; k0 += 32) {
      __syncthreads();
      {  // stage SB: one float4 per thread
        int c = tid >> 3, q = (tid & 7) * 4;
        *(float4*)&SB[c][q] = *(const float4*)(M + (size_t)(J + c) * D_ + k0 + q);
      }
      __syncthreads();
      if (gact) {
        #pragma unroll
        for (int q = 0; q < 8; ++q) {
          float4 b0 = *(const float4*)&SB[tc     ][q*4];
          float4 b1 = *(const float4*)&SB[tc +  8][q*4];
          float4 b2 = *(const float4*)&SB[tc + 16][q*4];
          float4 b3 = *(const float4*)&SB[tc + 24][q*4];
          #pragma unroll
          for (int r = 0; r < 8; ++r) {
            float4 a = *(const float4*)(M + (size_t)(gi0 + r) * D_ + k0 + q*4);
            acc[r][0] = fmaf(a.x,b0.x,acc[r][0]); acc[r][0] = fmaf(a.y,b0.y,acc[r][0]);
            acc[r][0] = fmaf(a.z,b0.z,acc[r][0]); acc[r][0] = fmaf(a.w,b0.w,acc[r][0]);
            acc[r][1] = fmaf(a.x,b1.x,acc[r][1]); acc[r][1] = fmaf(a.y,b1.y,acc[r][1]);
            acc[r][1] = fmaf(a.z,b1.z,acc[r][1]); acc[r][1] = fmaf(a.w,b1.w,acc[r][1]);
            acc[r][2] = fmaf(a.x,b2.x,acc[r][2]); acc[r][2] = fmaf(a.y,b2.y,acc[r][2]);
            acc[r][2] = fmaf(a.z,b2.z,acc[r][2]); acc[r][2] = fmaf(a.w,b2.w,acc[r][2]);
            acc[r][3] = fmaf(a.x,b3.x,acc[r][3]); acc[r][3] = fmaf(a.y,b3.y,acc[r][3]);
            acc[r][3] = fmaf(a.z,b3.z,acc[r][3]); acc[r][3] = fmaf(a.w,b3.w,acc[r][3]);
          }
        }
      }
    }
    __syncthreads();   // Pbuf staging + all GEMM chunks done
    // ---- apply Schur update into Pbuf (disjoint per-thread entries) ----
    if (gact && J > 0) {
      #pragma unroll
      for (int r = 0; r < 8; ++r)
        #pragma unroll
        for (int o = 0; o < 4; ++o)
          Pbuf[gi0 + r][tc + 8*o] -= acc[r][o];
    }
    __syncthreads();
    // ---- wave-synchronous factor of 32x32 diag block (lanes 0..31, registers+shfl) ----
    if (tid < 32) {
      const int r = tid;
      float a[CNB];
      #pragma unroll
      for (int q = 0; q < CNB; q += 4) {
        float4 f = *(const float4*)&Pbuf[J + r][q];
        a[q]=f.x; a[q+1]=f.y; a[q+2]=f.z; a[q+3]=f.w;
      }
      #pragma unroll
      for (int j = 0; j < CNB; ++j) {
        float ajj = __shfl(a[j], j);
        float d = sqrtf(ajj);
        float dinv = 1.0f / d;
        float lcol = (r == j) ? d : a[j] * dinv;
        a[j] = lcol;
        if (r == j) PDinv[j] = dinv;
        PLT[j][r] = (r > j) ? lcol : 0.f;    // transposed strictly-lower row j
        #pragma unroll
        for (int k = j + 1; k < CNB; ++k) {
          float lkj = __shfl(lcol, k);
          a[k] = fmaf(-lcol, lkj, a[k]);
        }
      }
      float* grow = M + (size_t)(J + r) * D_ + J;
      #pragma unroll
      for (int q = 0; q < CNB; q += 4) {
        float4 o;
        o.x = (q   <= r) ? a[q]   : 0.f;
        o.y = (q+1 <= r) ? a[q+1] : 0.f;
        o.z = (q+2 <= r) ? a[q+2] : 0.f;
        o.w = (q+3 <= r) ? a[q+3] : 0.f;
        *(float4*)(grow + q) = o;
      }
    }
    __syncthreads();
    // ---- TRSM rows J+32..255: right-looking, PLT rows are wave-uniform broadcasts ----
    const int nb = D_ - J - CNB;
    if (tid < nb) {
      const int gi = J + CNB + tid;
      float rr[CNB];
      #pragma unroll
      for (int q = 0; q < CNB; q += 4) {
        float4 f = *(const float4*)&Pbuf[gi][q];
        rr[q]=f.x; rr[q+1]=f.y; rr[q+2]=f.z; rr[q+3]=f.w;
      }
      #pragma unroll
      for (int j = 0; j < CNB; ++j) {
        float xj = rr[j] * PDinv[j];
        rr[j] = xj;
        #pragma unroll
        for (int q = 0; q < 8; ++q) {
          if (q >= (j >> 2)) {               // quads covering k>j (PLT zero-padded below)
            float4 p = *(const float4*)&PLT[j][q*4];
            rr[q*4+0] = fmaf(-xj, p.x, rr[q*4+0]);
            rr[q*4+1] = fmaf(-xj, p.y, rr[q*4+1]);
            rr[q*4+2] = fmaf(-xj, p.z, rr[q*4+2]);
            rr[q*4+3] = fmaf(-xj, p.w, rr[q*4+3]);
          }
        }
      }
      float* grow = M + (size_t)gi * D_ + J;
      #pragma unroll
      for (int q = 0; q < CNB; q += 4)
        *(float4*)(grow + q) = make_float4(rr[q], rr[q+1], rr[q+2], rr[q+3]);
    }
  }
  __syncthreads();
  // vectorized upper-triangle zeroing: row tid, cols tid+1..255
  {
    float* rowt = M + (size_t)tid * D_;
    int k = tid + 1;
    while (k < D_ && (k & 3)) rowt[k++] = 0.f;
    const float4 z4 = make_float4(0.f, 0.f, 0.f, 0.f);
    for (; k < D_; k += 4) *(float4*)(rowt + k) = z4;
  }
}

// ---------------- transpose A,V (f32 [b][t][d]) -> bf16 [b][d][T] ----------------
__global__ __launch_bounds__(256) void trans_k(const float* __restrict__ A,
    const float* __restrict__ V, __bf16* __restrict__ At, __bf16* __restrict__ Vt) {
  const float* X = blockIdx.z ? V : A;
  __bf16* Xt = blockIdx.z ? Vt : At;
  int b = blockIdx.y, t0 = blockIdx.x * 64, tid = threadIdx.x;
  __shared__ __bf16 TT[64 * 264];
  #pragma unroll
  for (int it = 0; it < 16; ++it) {
    int flat = it*1024 + tid*4;
    int t = flat >> 8, c = flat & 255;
    float4 f = *(const float4*)(X + ((size_t)b*T_ + t0 + t)*D_ + c);
    bf16x4 u;
    u[0] = (__bf16)f.x; u[1] = (__bf16)f.y; u[2] = (__bf16)f.z; u[3] = (__bf16)f.w;
    *(bf16x4*)&TT[t*264 + c] = u;
  }
  __syncthreads();
  int d = tid;
  __bf16* orow = Xt + ((size_t)b*D_ + d)*T_ + t0;
  #pragma unroll
  for (int g = 0; g < 8; ++g) {
    bf16x8 o;
    #pragma unroll
    for (int j = 0; j < 8; ++j) o[j] = TT[(g*8 + j)*264 + d];
    *(bf16x8*)(orow + g*8) = o;
  }
}

// ---------------- K16 = bf16(mu + eps @ L^T), register-tiled, eps/L staged [dd][*] ----------------
__global__ __launch_bounds__(256) void kgen_k(const float* __restrict__ L,
    const float* __restrict__ mu, __bf16* __restrict__ Kout, uint32_t key) {
  __shared__ float eps_s[16 * 64];    // [dd][t]
  __shared__ float L_s[16 * 256];     // [dd][e]
  const int b  = blockIdx.y;
  const int t0 = blockIdx.x * 64;
  const int tid = threadIdx.x;
  const int tt = tid >> 4;            // 0..15
  const int te = tid & 15;            // 0..15
  const int tg = tid & 63;            // eps-gen t
  const int dg = (tid >> 6) * 4;      // eps-gen dd base
  float acc[4][16];
  #pragma unroll
  for (int eq = 0; eq < 4; ++eq)
    #pragma unroll
    for (int i = 0; i < 16; ++i) acc[eq][i] = 0.f;

  for (int d0 = 0; d0 < D_; d0 += 16) {
    __syncthreads();
    uint32_t nbase = ((uint32_t)(b*T_ + t0 + tg))*256u + (uint32_t)(d0 + dg);
    #pragma unroll
    for (int q = 0; q < 4; ++q)
      eps_s[(dg + q)*64 + tg] = jax_normal_elem(key, nbase + q);
    {
      const float* lrow = L + (size_t)b*D_*D_ + (size_t)tid*D_ + d0;
      #pragma unroll
      for (int q = 0; q < 4; ++q) {
        float4 f = *(const float4*)(lrow + q*4);
        L_s[(q*4+0)*256 + tid] = f.x;
        L_s[(q*4+1)*256 + tid] = f.y;
        L_s[(q*4+2)*256 + tid] = f.z;
        L_s[(q*4+3)*256 + tid] = f.w;
      }
    }
    __syncthreads();
    #pragma unroll
    for (int dd = 0; dd < 16; ++dd) {
      float4 ep = *(const float4*)&eps_s[dd*64 + 4*tt];
      #pragma unroll
      for (int eq = 0; eq < 4; ++eq) {
        float4 lf = *(const float4*)&L_s[dd*256 + eq*64 + 4*te];
        acc[eq][0]  = fmaf(ep.x, lf.x, acc[eq][0]);  acc[eq][1]  = fmaf(ep.x, lf.y, acc[eq][1]);
        acc[eq][2]  = fmaf(ep.x, lf.z, acc[eq][2]);  acc[eq][3]  = fmaf(ep.x, lf.w, acc[eq][3]);
        acc[eq][4]  = fmaf(ep.y, lf.x, acc[eq][4]);  acc[eq][5]  = fmaf(ep.y, lf.y, acc[eq][5]);
        acc[eq][6]  = fmaf(ep.y, lf.z, acc[eq][6]);  acc[eq][7]  = fmaf(ep.y, lf.w, acc[eq][7]);
        acc[eq][8]  = fmaf(ep.z, lf.x, acc[eq][8]);  acc[eq][9]  = fmaf(ep.z, lf.y, acc[eq][9]);
        acc[eq][10] = fmaf(ep.z, lf.z, acc[eq][10]); acc[eq][11] = fmaf(ep.z, lf.w, acc[eq][11]);
        acc[eq][12] = fmaf(ep.w, lf.x, acc[eq][12]); acc[eq][13] = fmaf(ep.w, lf.y, acc[eq][13]);
        acc[eq][14] = fmaf(ep.w, lf.z, acc[eq][14]); acc[eq][15] = fmaf(ep.w, lf.w, acc[eq][15]);
      }
    }
  }
  #pragma unroll
  for (int eq = 0; eq < 4; ++eq) {
    float4 m4 = *(const float4*)(mu + b*D_ + eq*64 + 4*te);
    #pragma unroll
    for (int i = 0; i < 4; ++i) {
      bf16x4 o;
      o[0] = (__bf16)(acc[eq][i*4+0] + m4.x);
      o[1] = (__bf16)(acc[eq][i*4+1] + m4.y);
      o[2] = (__bf16)(acc[eq][i*4+2] + m4.z);
      o[3] = (__bf16)(acc[eq][i*4+3] + m4.w);
      *(bf16x4*)(Kout + ((size_t)b*T_ + t0 + 4*tt + i)*D_ + eq*64 + 4*te) = o;
    }
  }
}

// ---------------- MFMA flash attention, all-bf16 staged: O = softmax(Q K^T / 16) V ----------------
#define SCALE_ 0.0625f
#define KSTR 264
#define VSTR 72
#define SFSTR 68
#define PSTR 72

__global__ __launch_bounds__(256, 2) void attn_mfma(const float* __restrict__ Qg,
    const __bf16* __restrict__ K16, const __bf16* __restrict__ Vt,
    __bf16* __restrict__ Og) {
  // LDS: [KS 33792 | Sf 17408 overlay] + VS 36864 + Ps 9216 + rowm/l/a 768 = 80640 B (2 blocks/CU)
  __shared__ __align__(16) char smem[80640];
  __bf16* KS = (__bf16*)smem;                      // [64][KSTR]
  float*  Sf = (float*)smem;                       // [64][SFSTR] (overlays KS)
  __bf16* VS = (__bf16*)(smem + 33792);            // [256][VSTR]
  __bf16* Ps = (__bf16*)(smem + 33792 + 36864);    // [64][PSTR]
  float* rowm = (float*)(smem + 33792 + 36864 + 9216);
  float* rowl = rowm + 64;
  float* rowa = rowm + 128;

  const int tid  = threadIdx.x;
  const int wv   = tid >> 6;
  const int lane = tid & 63;
  const int ln31 = lane & 31;
  const int h8   = (lane >> 5) * 8;
  const int qb   = (wv >> 1) * 32;
  const int sb   = (wv & 1) * 32;
  const int cb   = (wv & 1) * 128;
  const int flat = blockIdx.x;
  const int b    = ((flat & 7) << 1) | ((flat >> 3) & 1);
  const int t0   = (flat >> 4) * 64;

  bf16x8 qf[16];
  {
    const float* qrow = Qg + ((size_t)b*T_ + t0 + qb + ln31) * D_;
    #pragma unroll
    for (int s = 0; s < 16; ++s) {
      float4 f0 = *(const float4*)(qrow + s*16 + h8);
      float4 f1 = *(const float4*)(qrow + s*16 + h8 + 4);
      bf16x8 q;
      q[0] = (__bf16)f0.x; q[1] = (__bf16)f0.y; q[2] = (__bf16)f0.z; q[3] = (__bf16)f0.w;
      q[4] = (__bf16)f1.x; q[5] = (__bf16)f1.y; q[6] = (__bf16)f1.z; q[7] = (__bf16)f1.w;
      qf[s] = q;
    }
  }
  if (tid < 64) { rowm[tid] = -INFINITY; rowl[tid] = 0.f; }

  float16 oacc[4];
  #pragma unroll
  for (int nb = 0; nb < 4; ++nb)
    #pragma unroll
    for (int i = 0; i < 16; ++i) oacc[nb][i] = 0.f;

  for (int s0 = 0; s0 < T_; s0 += 64) {
    __syncthreads();
    #pragma unroll
    for (int it = 0; it < 8; ++it) {
      int fl = it*256 + tid;
      int r = fl >> 5, c8 = (fl & 31) * 8;
      *(bf16x8*)&KS[r*KSTR + c8] =
          *(const bf16x8*)(K16 + ((size_t)b*T_ + s0 + r)*D_ + c8);
    }
    #pragma unroll
    for (int it = 0; it < 8; ++it) {
      int fl = it*256 + tid;
      int d = fl >> 3, sc = (fl & 7) * 8;
      *(bf16x8*)&VS[d*VSTR + sc] =
          *(const bf16x8*)(Vt + ((size_t)b*D_ + d)*T_ + s0 + sc);
    }
    __syncthreads();
    float16 sacc = {0.f,0.f,0.f,0.f,0.f,0.f,0.f,0.f,0.f,0.f,0.f,0.f,0.f,0.f,0.f,0.f};
    #pragma unroll
    for (int d = 0; d < 16; ++d) {
      bf16x8 kf = *(const bf16x8*)&KS[(sb + ln31)*KSTR + d*16 + h8];
      sacc = __builtin_amdgcn_mfma_f32_32x32x16_bf16(qf[d], kf, sacc, 0, 0, 0);
    }
    __syncthreads();
    #pragma unroll
    for (int r = 0; r < 16; ++r) {
      int row = qb + (r & 3) + 8*(r >> 2) + 4*(lane >> 5);
      Sf[row*SFSTR + sb + ln31] = sacc[r] * SCALE_;
    }
    __syncthreads();
    {
      int r = tid >> 2, sub = tid & 3;
      const float* srow = &Sf[r*SFSTR + sub*16];
      float4 a0 = *(const float4*)(srow);
      float4 a1 = *(const float4*)(srow + 4);
      float4 a2 = *(const float4*)(srow + 8);
      float4 a3 = *(const float4*)(srow + 12);
      float xv[16] = {a0.x,a0.y,a0.z,a0.w, a1.x,a1.y,a1.z,a1.w,
                      a2.x,a2.y,a2.z,a2.w, a3.x,a3.y,a3.z,a3.w};
      float mloc = xv[0];
      #pragma unroll
      for (int i = 1; i < 16; ++i) mloc = fmaxf(mloc, xv[i]);
      mloc = fmaxf(mloc, __shfl_xor(mloc, 1));
      mloc = fmaxf(mloc, __shfl_xor(mloc, 2));
      float mold = rowm[r];
      float mnew = fmaxf(mold, mloc);
      float ls = 0.f;
      #pragma unroll
      for (int i = 0; i < 16; ++i) { xv[i] = expf(xv[i] - mnew); ls += xv[i]; }
      #pragma unroll
      for (int i = 0; i < 8; ++i) {
        bf16x2 t2; t2[0] = (__bf16)xv[2*i]; t2[1] = (__bf16)xv[2*i+1];
        *(bf16x2*)&Ps[r*PSTR + sub*16 + 2*i] = t2;
      }
      ls += __shfl_xor(ls, 1);
      ls += __shfl_xor(ls, 2);
      if (sub == 0) {
        float al = expf(mold - mnew);
        rowa[r] = al;
        rowl[r] = rowl[r] * al + ls;
        rowm[r] = mnew;
      }
    }
    __syncthreads();
    #pragma unroll
    for (int r = 0; r < 16; ++r) {
      float al = rowa[qb + (r & 3) + 8*(r >> 2) + 4*(lane >> 5)];
      oacc[0][r] *= al; oacc[1][r] *= al; oacc[2][r] *= al; oacc[3][r] *= al;
    }
    #pragma unroll
    for (int ks = 0; ks < 4; ++ks) {
      bf16x8 pf = *(const bf16x8*)&Ps[(qb + ln31)*PSTR + ks*16 + h8];
      #pragma unroll
      for (int nb = 0; nb < 4; ++nb) {
        bf16x8 vf = *(const bf16x8*)&VS[(cb + nb*32 + ln31)*VSTR + ks*16 + h8];
        oacc[nb] = __builtin_amdgcn_mfma_f32_32x32x16_bf16(pf, vf, oacc[nb], 0, 0, 0);
      }
    }
  }
  #pragma unroll
  for (int r = 0; r < 16; ++r) {
    int row = qb + (r & 3) + 8*(r >> 2) + 4*(lane >> 5);
    float inv = 1.0f / rowl[row];
    __bf16* orow = Og + ((size_t)b*T_ + t0 + row)*D_ + cb + ln31;
    orow[0]  = (__bf16)(oacc[0][r] * inv);
    orow[32] = (__bf16)(oacc[1][r] * inv);
    orow[64] = (__bf16)(oacc[2][r] * inv);
    orow[96] = (__bf16)(oacc[3][r] * inv);
  }
}

// ---------------- gates + cosine combine (att inputs bf16) ----------------
__global__ __launch_bounds__(256) void comb_k(const float* __restrict__ A,
    const float* __restrict__ Vv, const __bf16* __restrict__ att1,
    const __bf16* __restrict__ att2, const float* __restrict__ WA,
    const float* __restrict__ WV, const float* __restrict__ bA,
    const float* __restrict__ bV, float* __restrict__ out) {
  int wv = threadIdx.x >> 6;
  int lane = threadIdx.x & 63;
  size_t row = (size_t)blockIdx.x * 4 + wv;
  size_t base = row * D_;
  int d = lane * 4;
  float4 a  = *(const float4*)(A + base + d);
  float4 v  = *(const float4*)(Vv + base + d);
  bf16x4 xb = *(const bf16x4*)(att1 + base + d);
  bf16x4 yb = *(const bf16x4*)(att2 + base + d);
  float4 x = make_float4((float)xb[0], (float)xb[1], (float)xb[2], (float)xb[3]);
  float4 y = make_float4((float)yb[0], (float)yb[1], (float)yb[2], (float)yb[3]);
  float4 w1 = *(const float4*)(WA + d);
  float4 w2 = *(const float4*)(WA + 256 + d);
  float4 w3 = *(const float4*)(WV + d);
  float4 w4 = *(const float4*)(WV + 256 + d);
  float sga = a.x*w1.x + a.y*w1.y + a.z*w1.z + a.w*w1.w
            + x.x*w2.x + x.y*w2.y + x.z*w2.z + x.w*w2.w;
  float sgv = v.x*w3.x + v.y*w3.y + v.z*w3.z + v.w*w3.w
            + y.x*w4.x + y.y*w4.y + y.z*w4.z + y.w*w4.w;
  float sav = a.x*v.x + a.y*v.y + a.z*v.z + a.w*v.w;
  float saa = a.x*a.x + a.y*a.y + a.z*a.z + a.w*a.w;
  float svv = v.x*v.x + v.y*v.y + v.z*v.z + v.w*v.w;
  #pragma unroll
  for (int m = 32; m; m >>= 1) {
    sga += __shfl_xor(sga, m);
    sgv += __shfl_xor(sgv, m);
    sav += __shfl_xor(sav, m);
    saa += __shfl_xor(saa, m);
    svv += __shfl_xor(svv, m);
  }
  float gA = 1.0f / (1.0f + expf(-(sga + bA[0])));
  float gV = 1.0f / (1.0f + expf(-(sgv + bV[0])));
  float cs = sav / fmaxf(sqrtf(saa) * sqrtf(svv), 1e-8f);
  float al = 1.0f / (1.0f + expf(-cs));
  float be = 1.0f - al;
  float4 o;
  o.x = al * (gA*a.x + (1.0f-gA)*x.x) + be * (gV*v.x + (1.0f-gV)*y.x);
  o.y = al * (gA*a.y + (1.0f-gA)*x.y) + be * (gV*v.y + (1.0f-gV)*y.y);
  o.z = al * (gA*a.z + (1.0f-gA)*x.z) + be * (gV*v.z + (1.0f-gV)*y.z);
  o.w = al * (gA*a.w + (1.0f-gA)*x.w) + be * (gV*v.w + (1.0f-gV)*y.w);
  *(float4*)(out + base + d) = o;
}

extern "C" void kernel_launch(void* const* d_in, const int* in_sizes, int n_in,
                              void* d_out, int out_size, void* d_ws, size_t ws_size,
                              hipStream_t stream) {
  (void)in_sizes; (void)n_in; (void)out_size; (void)ws_size;
  const float* A  = (const float*)d_in[0];
  const float* V  = (const float*)d_in[1];
  const float* WA = (const float*)d_in[2];
  const float* WV = (const float*)d_in[3];
  const float* bA = (const float*)d_in[4];
  const float* bV = (const float*)d_in[5];
  float* ws  = (float*)d_ws;
  float*  muA  = ws;                                   // 4096 f
  float*  muV  = muA + 4096;                           // 4096 f
  float*  LA   = muV + 4096;                           // 1,048,576 f
  float*  LV   = LA + (size_t)B_*D_*D_;                // 1,048,576 f
  __bf16* K16  = (__bf16*)(LV + (size_t)B_*D_*D_);     // N_ bf16 (N_/2 f-slots)
  __bf16* At16 = (__bf16*)((float*)K16 + N_/2);        // N_ bf16
  __bf16* Vt16 = (__bf16*)((float*)At16 + N_/2);       // N_ bf16
  __bf16* at1  = (__bf16*)((float*)Vt16 + N_/2);       // N_ bf16
  __bf16* at2  = (__bf16*)((float*)at1 + N_/2);        // N_ bf16

  mean_k<<<dim3(16,2), dim3(1024), 0, stream>>>(A, V, muA, muV);
  sigma_k<<<dim3(10,16,2), dim3(256), 0, stream>>>(A, V, muA, muV, LA, LV);
  chol_k<<<dim3(16,2), dim3(256), 0, stream>>>(LA, LV);
  trans_k<<<dim3(32,16,2), dim3(256), 0, stream>>>(A, V, At16, Vt16);
  // K_v = resample(V, key 42): audio queries attend to it, values = V
  kgen_k<<<dim3(32,16), dim3(256), 0, stream>>>(LV, muV, K16, 42u);
  attn_mfma<<<dim3(512), dim3(256), 0, stream>>>(A, K16, Vt16, at1);
  // K_a = resample(A, key 43): visual queries attend to it, values = A
  kgen_k<<<dim3(32,16), dim3(256), 0, stream>>>(LA, muA, K16, 43u);
  attn_mfma<<<dim3(512), dim3(256), 0, stream>>>(V, K16, At16, at2);
  comb_k<<<dim3(8192), dim3(256), 0, stream>>>(A, V, at1, at2, WA, WV, bA, bV, (float*)d_out);
}